// Round 8
// baseline (2515.998 us; speedup 1.0000x reference)
//
#include <hip/hip_runtime.h>

#define NTOK 2048      // BATCH*SEQ
#define SEQL 1024
#define DMODEL 1024
#define DINNER 2048
#define DSTATE 16
#define DTRANK 64
#define GCH 64         // scan chunks
#define LC 16          // steps per chunk
#define XDS 128        // padded xp-GEMM N (96 -> 128)
#define XSPK 8         // x_proj split-K factor (proven config)

typedef __attribute__((ext_vector_type(8))) short short8;
typedef __attribute__((ext_vector_type(4))) float float4v;

__device__ __forceinline__ unsigned short f2bf(float f) {
    unsigned u = __float_as_uint(f);
    unsigned r = u + 0x7FFFu + ((u >> 16) & 1u);
    return (unsigned short)(r >> 16);
}
__device__ __forceinline__ float bf2f(unsigned short h) {
    return __uint_as_float(((unsigned)h) << 16);
}

// Device-scope grid barrier. SAFE ONLY when the whole grid is co-resident:
// scan_fused is 1024 blocks x 256 thr, __launch_bounds__(256,4) caps VGPR at 128
// -> 4 blocks/CU x 256 CU = 1024, exact fit. Monotonic targets on one counter
// (never reset mid-launch) -> no sense reversal, no reuse hazard.
__device__ __forceinline__ void grid_bar(unsigned* cnt, unsigned target) {
    __syncthreads();
    if (threadIdx.x == 0) {
        __threadfence();                       // device-scope release of prior writes
        atomicAdd(cnt, 1u);                    // device-scope (m20)
        while (__hip_atomic_load(cnt, __ATOMIC_ACQUIRE, __HIP_MEMORY_SCOPE_AGENT)
               < target)
            __builtin_amdgcn_s_sleep(8);
    }
    __syncthreads();
}

// ---------------- fused f32 -> bf16 weight conversion, 16 elems/thread ----------------
// Also zeroes the grid-barrier counter (stream order makes it visible to scan_fused).
__global__ __launch_bounds__(256) void f32_to_bf16_4(
    const float* __restrict__ s0, unsigned short* __restrict__ d0, int c0,
    const float* __restrict__ s1, unsigned short* __restrict__ d1, int c1,
    const float* __restrict__ s2, unsigned short* __restrict__ d2, int c2,
    const float* __restrict__ s3, unsigned short* __restrict__ d3, int c3,
    unsigned* __restrict__ bar) {
    int i = blockIdx.x * 256 + threadIdx.x;      // i indexes 16-elem groups
    if (i == 0) *bar = 0u;
    if (i >= c3) return;
    const float* s; unsigned short* dd; int j;
    if (i < c0)      { s = s0; dd = d0; j = i; }
    else if (i < c1) { s = s1; dd = d1; j = i - c0; }
    else if (i < c2) { s = s2; dd = d2; j = i - c1; }
    else             { s = s3; dd = d3; j = i - c2; }
    float4 a = ((const float4*)s)[4 * j];
    float4 b = ((const float4*)s)[4 * j + 1];
    float4 c = ((const float4*)s)[4 * j + 2];
    float4 d = ((const float4*)s)[4 * j + 3];
    uint4 v0, v1;
    v0.x = (unsigned)f2bf(a.x) | ((unsigned)f2bf(a.y) << 16);
    v0.y = (unsigned)f2bf(a.z) | ((unsigned)f2bf(a.w) << 16);
    v0.z = (unsigned)f2bf(b.x) | ((unsigned)f2bf(b.y) << 16);
    v0.w = (unsigned)f2bf(b.z) | ((unsigned)f2bf(b.w) << 16);
    v1.x = (unsigned)f2bf(c.x) | ((unsigned)f2bf(c.y) << 16);
    v1.y = (unsigned)f2bf(c.z) | ((unsigned)f2bf(c.w) << 16);
    v1.z = (unsigned)f2bf(d.x) | ((unsigned)f2bf(d.y) << 16);
    v1.w = (unsigned)f2bf(d.z) | ((unsigned)f2bf(d.w) << 16);
    ((uint4*)dd)[2 * j]     = v0;
    ((uint4*)dd)[2 * j + 1] = v1;
}

// ---------------- LayerNorm (prologue): f32 in -> bf16 out, also copies x into x_res ----------------
__global__ __launch_bounds__(256) void ln_kernel(
    const float* __restrict__ x, float* __restrict__ x_copy,
    const float* __restrict__ g, const float* __restrict__ b,
    unsigned short* __restrict__ out_bf) {
    int row = blockIdx.x;
    int t = threadIdx.x;
    float4 v = ((const float4*)(x + (size_t)row * DMODEL))[t];
    ((float4*)(x_copy + (size_t)row * DMODEL))[t] = v;
    float s  = v.x + v.y + v.z + v.w;
    float ss = v.x*v.x + v.y*v.y + v.z*v.z + v.w*v.w;
    for (int o = 32; o; o >>= 1) { s += __shfl_xor(s, o); ss += __shfl_xor(ss, o); }
    __shared__ float red[8];
    int wv = t >> 6;
    if ((t & 63) == 0) { red[wv * 2] = s; red[wv * 2 + 1] = ss; }
    __syncthreads();
    s  = red[0] + red[2] + red[4] + red[6];
    ss = red[1] + red[3] + red[5] + red[7];
    float mu = s * (1.f / DMODEL);
    float rstd = rsqrtf(ss * (1.f / DMODEL) - mu * mu + 1e-5f);
    float4 gv = ((const float4*)g)[t];
    float4 bv = ((const float4*)b)[t];
    ((ushort4*)out_bf)[row * 256 + t] = make_ushort4(
        f2bf((v.x - mu) * rstd * gv.x + bv.x),
        f2bf((v.y - mu) * rstd * gv.y + bv.y),
        f2bf((v.z - mu) * rstd * gv.z + bv.z),
        f2bf((v.w - mu) * rstd * gv.w + bv.w));
}

// ---------------- fused: x_res += p0+p1+p2+p3 ; LN(x_res) -> bf16 (or f32 final) ----------------
__global__ __launch_bounds__(256) void residual_ln(
    float* __restrict__ x_res, const float* __restrict__ p0,
    const float* __restrict__ p1, const float* __restrict__ p2,
    const float* __restrict__ p3, const float* __restrict__ g,
    const float* __restrict__ b, unsigned short* __restrict__ out_bf,
    float* __restrict__ out_f32) {
    int row = blockIdx.x;
    int t = threadIdx.x;
    size_t o4 = (size_t)row * 256 + t;
    float4 v  = ((const float4*)x_res)[o4];
    float4 a0 = ((const float4*)p0)[o4];
    float4 a1 = ((const float4*)p1)[o4];
    float4 a2 = ((const float4*)p2)[o4];
    float4 a3 = ((const float4*)p3)[o4];
    v.x += (a0.x + a1.x) + (a2.x + a3.x);
    v.y += (a0.y + a1.y) + (a2.y + a3.y);
    v.z += (a0.z + a1.z) + (a2.z + a3.z);
    v.w += (a0.w + a1.w) + (a2.w + a3.w);
    ((float4*)x_res)[o4] = v;
    float s  = v.x + v.y + v.z + v.w;
    float ss = v.x*v.x + v.y*v.y + v.z*v.z + v.w*v.w;
    for (int o = 32; o; o >>= 1) { s += __shfl_xor(s, o); ss += __shfl_xor(ss, o); }
    __shared__ float red[8];
    int wv = t >> 6;
    if ((t & 63) == 0) { red[wv * 2] = s; red[wv * 2 + 1] = ss; }
    __syncthreads();
    s  = red[0] + red[2] + red[4] + red[6];
    ss = red[1] + red[3] + red[5] + red[7];
    float mu = s * (1.f / DMODEL);
    float rstd = rsqrtf(ss * (1.f / DMODEL) - mu * mu + 1e-5f);
    float4 gv = ((const float4*)g)[t];
    float4 bv = ((const float4*)b)[t];
    float o0 = (v.x - mu) * rstd * gv.x + bv.x;
    float o1 = (v.y - mu) * rstd * gv.y + bv.y;
    float o2 = (v.z - mu) * rstd * gv.z + bv.z;
    float o3 = (v.w - mu) * rstd * gv.w + bv.w;
    if (out_f32) {
        ((float4*)out_f32)[o4] = make_float4(o0, o1, o2, o3);
    } else {
        ((ushort4*)out_bf)[o4] = make_ushort4(f2bf(o0), f2bf(o1), f2bf(o2), f2bf(o3));
    }
}

// ---------------- GEMM: C[M,N] = A[M,K](bf16) * B[N,K]^T(bf16) ----------------
// 128x64 tile, 4 waves, depth-3 LDS pipeline (36 KB -> 4 blocks/CU).
// Modes: 0 = f32 store into partial z (Cv + z*M*N); 2 = bf16 store;
// 3 = bf16 store of softplus(acc + bias[col]).
// R6 note: atomic accumulate (old mode 4) across split-K XCDs was a 4x regression.
#define BKG 32
__global__ __launch_bounds__(256) void gemm64(
    const unsigned short* __restrict__ A, const unsigned short* __restrict__ B,
    void* __restrict__ Cv, const float* __restrict__ bias,
    int M, int N, int K, int Nb, int mode) {
    __shared__ __attribute__((aligned(16))) unsigned short As[3][128 * BKG];
    __shared__ __attribute__((aligned(16))) unsigned short Bs[3][64 * BKG];
    int m0 = blockIdx.y * 128, n0 = blockIdx.x * 64;
    int Klocal = K / gridDim.z;
    int kstart = blockIdx.z * Klocal;
    int t = threadIdx.x;
    int lane = t & 63, w = t >> 6;
    int tr = lane & 15, quad = lane >> 4;
    int r_l = lane >> 2;
    int q_l = (lane & 3) ^ ((lane >> 3) & 3);      // swizzled 16B-unit
    int col_l = q_l * 8;

    float4v acc[2][4];
    for (int mi = 0; mi < 2; ++mi)
        for (int ni = 0; ni < 4; ++ni)
            acc[mi][ni] = (float4v){0.f, 0.f, 0.f, 0.f};

    auto stage = [&](int kt, int buf) {
        int kbase = kstart + kt * BKG;
#pragma unroll
        for (int j = 0; j < 2; ++j) {
            int c = w * 2 + j;
            const unsigned short* ga = A + (size_t)(m0 + c * 16 + r_l) * K + kbase + col_l;
            __builtin_amdgcn_global_load_lds(
                (const __attribute__((address_space(1))) void*)ga,
                (__attribute__((address_space(3))) void*)(&As[buf][c * 512]),
                16, 0, 0);
        }
        int brow = n0 + w * 16 + r_l;
        if (brow >= Nb) brow = Nb - 1;
        const unsigned short* gb = B + (size_t)brow * K + kbase + col_l;
        __builtin_amdgcn_global_load_lds(
            (const __attribute__((address_space(1))) void*)gb,
            (__attribute__((address_space(3))) void*)(&Bs[buf][w * 512]),
            16, 0, 0);
    };

    int KT = Klocal / BKG;
    stage(0, 0);
    if (KT > 1) stage(1, 1);
    int u_off = (tr * 4 + (quad ^ ((tr >> 1) & 3))) * 8;
    for (int kt = 0; kt < KT; ++kt) {
        int cur = kt % 3;
        if (kt + 2 < KT) stage(kt + 2, (kt + 2) % 3);
        asm volatile("" ::: "memory");
        int nleft = KT - kt - 1;
        if (nleft >= 2)      __builtin_amdgcn_s_waitcnt(0x0F76);  // vmcnt(6)
        else if (nleft == 1) __builtin_amdgcn_s_waitcnt(0x0F73);  // vmcnt(3)
        else                 __builtin_amdgcn_s_waitcnt(0x0F70);  // vmcnt(0)
        __builtin_amdgcn_s_barrier();
        asm volatile("" ::: "memory");
        short8 af[2], bfr[4];
#pragma unroll
        for (int i = 0; i < 2; ++i)
            af[i] = *(const short8*)(&As[cur][(w * 2 + i) * 512 + u_off]);
#pragma unroll
        for (int i = 0; i < 4; ++i)
            bfr[i] = *(const short8*)(&Bs[cur][i * 512 + u_off]);
#pragma unroll
        for (int mi = 0; mi < 2; ++mi)
#pragma unroll
            for (int ni = 0; ni < 4; ++ni)
                acc[mi][ni] = __builtin_amdgcn_mfma_f32_16x16x32_bf16(
                    af[mi], bfr[ni], acc[mi][ni], 0, 0, 0);
        asm volatile("" ::: "memory");
        __builtin_amdgcn_s_barrier();
        asm volatile("" ::: "memory");
    }
    // C/D layout (m89-verified): col = lane&15, row = (lane>>4)*4 + reg
    size_t zoff = (size_t)blockIdx.z * M * N;
    for (int mi = 0; mi < 2; ++mi)
        for (int ni = 0; ni < 4; ++ni) {
            int col = n0 + ni * 16 + tr;
            int rowb = m0 + w * 32 + mi * 16 + quad * 4;
            for (int r = 0; r < 4; ++r) {
                size_t off = (size_t)(rowb + r) * N + col;
                float val = acc[mi][ni][r];
                if (mode == 0) {
                    ((float*)Cv)[zoff + off] = val;
                } else if (mode == 2) {
                    ((unsigned short*)Cv)[off] = f2bf(val);
                } else {
                    float v2 = val + bias[col];
                    float sp = (v2 > 15.f) ? v2 : log1pf(expf(v2));
                    ((unsigned short*)Cv)[off] = f2bf(sp);
                }
            }
        }
}

// ---------------- reduce 8 xp partials -> dtA(bf16) + compact BC(f32) ----------------
__global__ __launch_bounds__(256) void reduce_xp(
    const float* __restrict__ part, unsigned short* __restrict__ dtA,
    float* __restrict__ BC) {
    int i = blockIdx.x * 256 + threadIdx.x;      // NTOK*128
    int row = i >> 7, col = i & 127;
    float s = 0.f;
#pragma unroll
    for (int z = 0; z < XSPK; ++z)
        s += part[(size_t)z * NTOK * XDS + i];
    if (col < 64) dtA[row * 64 + col] = f2bf(s);
    else if (col < 96) BC[row * 32 + (col - 64)] = s;
}

// ---------------- causal depthwise conv(4) + bias + silu; bf16 -> bf16, 8 ch/thread ----------------
__global__ __launch_bounds__(256) void conv_silu(
    const unsigned short* __restrict__ xz, const float* __restrict__ cw,
    const float* __restrict__ cb, unsigned short* __restrict__ xm_bf) {
    int i = blockIdx.x * 256 + threadIdx.x;   // NTOK * DINNER/8
    int c8 = i & (DINNER / 8 - 1);
    int tk = i >> 8;
    int l = tk & (SEQL - 1);
    int c = c8 * 8;
    const unsigned short* base = xz + (size_t)tk * (2 * DINNER) + c;
    short8 r3 = {0,0,0,0,0,0,0,0}, r2 = {0,0,0,0,0,0,0,0}, r1 = {0,0,0,0,0,0,0,0};
    if (l >= 3) r3 = *(const short8*)(base - 3 * 2 * DINNER);
    if (l >= 2) r2 = *(const short8*)(base - 2 * 2 * DINNER);
    if (l >= 1) r1 = *(const short8*)(base - 1 * 2 * DINNER);
    short8 r0 = *(const short8*)(base);
    short8 out;
#pragma unroll
    for (int j = 0; j < 8; ++j) {
        float4 wv = ((const float4*)cw)[c + j];
        float acc = cb[c + j]
            + bf2f((unsigned short)r3[j]) * wv.x
            + bf2f((unsigned short)r2[j]) * wv.y
            + bf2f((unsigned short)r1[j]) * wv.z
            + bf2f((unsigned short)r0[j]) * wv.w;
        float sv = acc / (1.f + expf(-acc));
        out[j] = (short)f2bf(sv);
    }
    *(short8*)(xm_bf + (size_t)tk * DINNER + c) = out;
}

// ---------------- fused scan: phase A (local) + grid bar + phase B (combine)
// + grid bar + phase C (seeded). Saves 2 dispatch boundaries/layer and BC/A_log
// restage. Grid MUST be 1024 blocks (co-residency; see grid_bar).
__global__ __launch_bounds__(256, 4) void scan_fused(
    const unsigned short* __restrict__ dt_bf, const unsigned short* __restrict__ xm_bf,
    const float* __restrict__ BC, const float* __restrict__ A_log,
    const float* __restrict__ D_skip, const unsigned short* __restrict__ xz,
    float* __restrict__ h_end, float* __restrict__ S_chunk,
    float* __restrict__ h_in, unsigned short* __restrict__ y_bf,
    unsigned* __restrict__ bar, unsigned tbase) {
    int bid = blockIdx.x;                 // 1024
    int g = bid >> 4, b = (bid >> 3) & 1, cbk = bid & 7;
    int c = cbk * 256 + threadIdx.x;
    __shared__ float BCsh[LC][32];
    for (int r = 0; r < 2; ++r) {
        int e = threadIdx.x + r * 256;
        int li = e >> 5, s = e & 31;
        BCsh[li][s] = BC[((size_t)(b * SEQL + g * LC + li)) * 32 + s];
    }
    __syncthreads();
    float a_l2[16], h[16];
#pragma unroll
    for (int s = 0; s < 16; ++s) {
        a_l2[s] = -expf(A_log[c * 16 + s]) * 1.44269504f;
        h[s] = 0.f;
    }
    // ---- phase A: local recurrence (h0 = 0) -> h_end, S ----
    float S = 0.f;
    int rowbase = b * SEQL + g * LC;
    for (int i = 0; i < LC; ++i) {
        size_t off = (size_t)(rowbase + i) * DINNER + c;
        float dtv = bf2f(dt_bf[off]);
        S += dtv;
        float u = bf2f(xm_bf[off]);
        float bu = dtv * u;
#pragma unroll
        for (int s = 0; s < 16; ++s) {
            float dA = exp2f(dtv * a_l2[s]);
            h[s] = dA * h[s] + BCsh[i][s] * bu;
        }
    }
    int gb = g * 2 + b;
#pragma unroll
    for (int s = 0; s < 16; ++s)
        h_end[((size_t)gb * 16 + s) * DINNER + c] = h[s];
    S_chunk[(size_t)gb * DINNER + c] = S;

    grid_bar(bar, tbase + 1024);

    // ---- phase B: combine chunks -> h_in (first 256 blocks only) ----
    if (bid < 256) {
        int idx = bid * 256 + threadIdx.x;     // 65536 threads
        int cc = idx & (DINNER - 1);
        int ss = (idx >> 11) & 15;
        int bb = idx >> 15;
        float al2 = -expf(A_log[cc * 16 + ss]) * 1.44269504f;
        float hh = 0.f;
        for (int gg = 0; gg < GCH; ++gg) {
            int gb2 = gg * 2 + bb;
            h_in[((size_t)gb2 * 16 + ss) * DINNER + cc] = hh;
            float P = exp2f(al2 * S_chunk[(size_t)gb2 * DINNER + cc]);
            hh = P * hh + h_end[((size_t)gb2 * 16 + ss) * DINNER + cc];
        }
    }

    grid_bar(bar, tbase + 2048);

    // ---- phase C: seeded recurrence -> y ----
#pragma unroll
    for (int s = 0; s < 16; ++s)
        h[s] = h_in[((size_t)gb * 16 + s) * DINNER + c];
    float dsk = D_skip[c];
    for (int i = 0; i < LC; ++i) {
        size_t off = (size_t)(rowbase + i) * DINNER + c;
        float dtv = bf2f(dt_bf[off]);
        float u = bf2f(xm_bf[off]);
        float bu = dtv * u;
        float y = 0.f;
#pragma unroll
        for (int s = 0; s < 16; ++s) {
            float dA = exp2f(dtv * a_l2[s]);
            h[s] = dA * h[s] + BCsh[i][s] * bu;
            y += h[s] * BCsh[i][16 + s];
        }
        y += u * dsk;
        float zv = bf2f(xz[(size_t)(rowbase + i) * (2 * DINNER) + DINNER + c]);
        y *= zv / (1.f + expf(-zv));
        y_bf[off] = f2bf(y);
    }
}

extern "C" void kernel_launch(void* const* d_in, const int* in_sizes, int n_in,
                              void* d_out, int out_size, void* d_ws, size_t ws_size,
                              hipStream_t stream) {
    const float* x_in   = (const float*)d_in[0];
    const float* in_w   = (const float*)d_in[1];
    const float* conv_w = (const float*)d_in[2];
    const float* conv_b = (const float*)d_in[3];
    const float* xp_w   = (const float*)d_in[4];
    const float* dt_w   = (const float*)d_in[5];
    const float* dt_b   = (const float*)d_in[6];
    const float* A_logp = (const float*)d_in[7];
    const float* Dsk    = (const float*)d_in[8];
    const float* out_w  = (const float*)d_in[9];
    const float* ln_g   = (const float*)d_in[10];
    const float* ln_b   = (const float*)d_in[11];
    float* outp = (float*)d_out;

    char* p = (char*)d_ws;
    auto alloc = [&](size_t bytes) {
        void* r = (void*)p;
        p += (bytes + 255) & ~(size_t)255;
        return r;
    };
    float* x_res  = (float*)alloc((size_t)NTOK * DMODEL * 4);
    unsigned short* xn_bf = (unsigned short*)alloc((size_t)NTOK * DMODEL * 2);
    unsigned short* xz_bf = (unsigned short*)alloc((size_t)NTOK * 2 * DINNER * 2);
    unsigned short* xm_bf = (unsigned short*)alloc((size_t)NTOK * DINNER * 2);
    float* xp_part = (float*)alloc((size_t)XSPK * NTOK * XDS * 4);
    float* out_part = (float*)alloc((size_t)4 * NTOK * DMODEL * 4);
    float* BC     = (float*)alloc((size_t)NTOK * 32 * 4);
    unsigned short* dtA_bf = (unsigned short*)alloc((size_t)NTOK * DTRANK * 2);
    unsigned short* dt_bf = (unsigned short*)alloc((size_t)NTOK * DINNER * 2);
    unsigned short* y_bf = (unsigned short*)alloc((size_t)NTOK * DINNER * 2);
    float* h_end  = (float*)alloc((size_t)GCH * 2 * 16 * DINNER * 4);
    float* h_in   = (float*)alloc((size_t)GCH * 2 * 16 * DINNER * 4);
    float* S_chunk = (float*)alloc((size_t)GCH * 2 * DINNER * 4);
    unsigned* bar = (unsigned*)alloc(256);
    int n_inw  = 4 * 2 * DINNER * DMODEL;
    int n_xpw  = 4 * 96 * DINNER;
    int n_dtw  = 4 * DINNER * DTRANK;
    int n_outw = 4 * DMODEL * DINNER;
    unsigned short* wbf_in  = (unsigned short*)alloc((size_t)n_inw * 2);
    unsigned short* wbf_xp  = (unsigned short*)alloc((size_t)n_xpw * 2);
    unsigned short* wbf_dt  = (unsigned short*)alloc((size_t)n_dtw * 2);
    unsigned short* wbf_out = (unsigned short*)alloc((size_t)n_outw * 2);

    // counts in 16-elem groups (all sizes divisible by 16)
    int c0 = n_inw / 16;
    int c1 = c0 + n_xpw / 16;
    int c2 = c1 + n_dtw / 16;
    int c3 = c2 + n_outw / 16;
    f32_to_bf16_4<<<(c3 + 255) / 256, 256, 0, stream>>>(
        in_w, wbf_in, c0, xp_w, wbf_xp, c1, dt_w, wbf_dt, c2, out_w, wbf_out, c3, bar);

    // LN also copies x into x_res (replaces the memcpy)
    ln_kernel<<<NTOK, 256, 0, stream>>>(x_in, x_res, ln_g, ln_b, xn_bf);

    for (int L = 0; L < 4; ++L) {
        const unsigned short* w_in  = wbf_in  + (size_t)L * 2 * DINNER * DMODEL;
        const float*          w_cv  = conv_w  + (size_t)L * DINNER * 4;
        const float*          b_cv  = conv_b  + (size_t)L * DINNER;
        const unsigned short* w_xp  = wbf_xp  + (size_t)L * 96 * DINNER;
        const unsigned short* w_dt  = wbf_dt  + (size_t)L * DINNER * DTRANK;
        const float*          b_dt  = dt_b    + (size_t)L * DINNER;
        const float*          al    = A_logp  + (size_t)L * DINNER * DSTATE;
        const float*          dskl  = Dsk     + (size_t)L * DINNER;
        const unsigned short* w_out = wbf_out + (size_t)L * DMODEL * DINNER;

        // in_proj: [2048 x 4096 x 1024] -> bf16, 128x64 tile, 1024 blocks (4/CU)
        gemm64<<<dim3(64, 16, 1), 256, 0, stream>>>(
            xn_bf, w_in, xz_bf, nullptr, NTOK, 2 * DINNER, DMODEL, 2 * DINNER, 2);
        conv_silu<<<NTOK * (DINNER / 8) / 256, 256, 0, stream>>>(xz_bf, w_cv, b_cv, xm_bf);
        // x_proj: [2048 x 128(96) x 2048], split-K 8 -> f32 partials
        gemm64<<<dim3(2, 16, XSPK), 256, 0, stream>>>(
            xm_bf, w_xp, xp_part, nullptr, NTOK, XDS, DINNER, 96, 0);
        reduce_xp<<<NTOK * XDS / 256, 256, 0, stream>>>(xp_part, dtA_bf, BC);
        // dt_proj: [2048 x 2048 x 64], fused bias+softplus -> bf16
        gemm64<<<dim3(32, 16, 1), 256, 0, stream>>>(
            dtA_bf, w_dt, dt_bf, b_dt, NTOK, DINNER, DTRANK, DINNER, 3);
        // fused scan (A + B + C with device-scope grid barriers)
        scan_fused<<<GCH * 16, 256, 0, stream>>>(
            dt_bf, xm_bf, BC, al, dskl, xz_bf, h_end, S_chunk, h_in, y_bf,
            bar, (unsigned)(L * 2048));
        // out_proj: [2048 x 1024 x 2048], split-K 4 -> 1024 blocks (4/CU), KT=16
        gemm64<<<dim3(16, 16, 4), 256, 0, stream>>>(
            y_bf, w_out, out_part, nullptr, NTOK, DMODEL, DINNER, DMODEL, 0);
        // fused: x_res += p0+p1+p2+p3; LN -> next xn (bf16) or final out (f32)
        residual_ln<<<NTOK, 256, 0, stream>>>(
            x_res, out_part, out_part + (size_t)NTOK * DMODEL,
            out_part + (size_t)2 * NTOK * DMODEL, out_part + (size_t)3 * NTOK * DMODEL,
            ln_g, ln_b, (L < 3) ? xn_bf : nullptr, (L < 3) ? nullptr : outp);
    }
}

// Round 9
// 962.086 us; speedup vs baseline: 2.6151x; 2.6151x over previous
//
#include <hip/hip_runtime.h>

#define NTOK 2048      // BATCH*SEQ
#define SEQL 1024
#define DMODEL 1024
#define DINNER 2048
#define DSTATE 16
#define DTRANK 64
#define GCH 64         // scan chunks
#define LC 16          // steps per chunk
#define XDS 128        // padded xp-GEMM N (96 -> 128)
#define XSPK 8         // x_proj split-K factor (proven config)

typedef __attribute__((ext_vector_type(8))) short short8;
typedef __attribute__((ext_vector_type(4))) float float4v;

__device__ __forceinline__ unsigned short f2bf(float f) {
    unsigned u = __float_as_uint(f);
    unsigned r = u + 0x7FFFu + ((u >> 16) & 1u);
    return (unsigned short)(r >> 16);
}
__device__ __forceinline__ float bf2f(unsigned short h) {
    return __uint_as_float(((unsigned)h) << 16);
}
// packed-bf16 halves of a uint -> float
__device__ __forceinline__ float bflo(unsigned u) { return __uint_as_float(u << 16); }
__device__ __forceinline__ float bfhi(unsigned u) { return __uint_as_float(u & 0xffff0000u); }

// ---------------- fused f32 -> bf16 weight conversion (in/xp/out), 16 elems/thread ----------------
__global__ __launch_bounds__(256) void f32_to_bf16_3(
    const float* __restrict__ s0, unsigned short* __restrict__ d0, int c0,
    const float* __restrict__ s1, unsigned short* __restrict__ d1, int c1,
    const float* __restrict__ s2, unsigned short* __restrict__ d2, int c2) {
    int i = blockIdx.x * 256 + threadIdx.x;      // i indexes 16-elem groups
    if (i >= c2) return;
    const float* s; unsigned short* dd; int j;
    if (i < c0)      { s = s0; dd = d0; j = i; }
    else if (i < c1) { s = s1; dd = d1; j = i - c0; }
    else             { s = s2; dd = d2; j = i - c1; }
    float4 a = ((const float4*)s)[4 * j];
    float4 b = ((const float4*)s)[4 * j + 1];
    float4 c = ((const float4*)s)[4 * j + 2];
    float4 d = ((const float4*)s)[4 * j + 3];
    uint4 v0, v1;
    v0.x = (unsigned)f2bf(a.x) | ((unsigned)f2bf(a.y) << 16);
    v0.y = (unsigned)f2bf(a.z) | ((unsigned)f2bf(a.w) << 16);
    v0.z = (unsigned)f2bf(b.x) | ((unsigned)f2bf(b.y) << 16);
    v0.w = (unsigned)f2bf(b.z) | ((unsigned)f2bf(b.w) << 16);
    v1.x = (unsigned)f2bf(c.x) | ((unsigned)f2bf(c.y) << 16);
    v1.y = (unsigned)f2bf(c.z) | ((unsigned)f2bf(c.w) << 16);
    v1.z = (unsigned)f2bf(d.x) | ((unsigned)f2bf(d.y) << 16);
    v1.w = (unsigned)f2bf(d.z) | ((unsigned)f2bf(d.w) << 16);
    ((uint4*)dd)[2 * j]     = v0;
    ((uint4*)dd)[2 * j + 1] = v1;
}

// ---------------- dt_proj weight: f32 [L][DINNER][64] -> bf16 transposed, pair-interleaved ----------------
// Output layout: uint word (r2*DINNER + c) holds rows {2*r2, 2*r2+1} of column c.
// One-time, 2 MB total.
__global__ __launch_bounds__(256) void cvt_dtT(
    const float* __restrict__ w, unsigned short* __restrict__ wT) {
    int idx = blockIdx.x * 256 + threadIdx.x;   // 4*64*2048 = 524288
    int c = idx & (DINNER - 1);
    int r = (idx >> 11) & 63;
    int l = idx >> 17;
    size_t lbase = (size_t)l * 64 * DINNER;
    wT[lbase + ((size_t)(r >> 1) * DINNER + c) * 2 + (r & 1)] =
        f2bf(w[(size_t)l * DINNER * 64 + (size_t)c * 64 + r]);
}

// ---------------- LayerNorm (prologue): f32 in -> bf16 out, also copies x into x_res ----------------
__global__ __launch_bounds__(256) void ln_kernel(
    const float* __restrict__ x, float* __restrict__ x_copy,
    const float* __restrict__ g, const float* __restrict__ b,
    unsigned short* __restrict__ out_bf) {
    int row = blockIdx.x;
    int t = threadIdx.x;
    float4 v = ((const float4*)(x + (size_t)row * DMODEL))[t];
    ((float4*)(x_copy + (size_t)row * DMODEL))[t] = v;
    float s  = v.x + v.y + v.z + v.w;
    float ss = v.x*v.x + v.y*v.y + v.z*v.z + v.w*v.w;
    for (int o = 32; o; o >>= 1) { s += __shfl_xor(s, o); ss += __shfl_xor(ss, o); }
    __shared__ float red[8];
    int wv = t >> 6;
    if ((t & 63) == 0) { red[wv * 2] = s; red[wv * 2 + 1] = ss; }
    __syncthreads();
    s  = red[0] + red[2] + red[4] + red[6];
    ss = red[1] + red[3] + red[5] + red[7];
    float mu = s * (1.f / DMODEL);
    float rstd = rsqrtf(ss * (1.f / DMODEL) - mu * mu + 1e-5f);
    float4 gv = ((const float4*)g)[t];
    float4 bv = ((const float4*)b)[t];
    ((ushort4*)out_bf)[row * 256 + t] = make_ushort4(
        f2bf((v.x - mu) * rstd * gv.x + bv.x),
        f2bf((v.y - mu) * rstd * gv.y + bv.y),
        f2bf((v.z - mu) * rstd * gv.z + bv.z),
        f2bf((v.w - mu) * rstd * gv.w + bv.w));
}

// ---------------- fused: x_res += p0+p1+p2+p3 ; LN(x_res) -> bf16 (or f32 final) ----------------
__global__ __launch_bounds__(256) void residual_ln(
    float* __restrict__ x_res, const float* __restrict__ p0,
    const float* __restrict__ p1, const float* __restrict__ p2,
    const float* __restrict__ p3, const float* __restrict__ g,
    const float* __restrict__ b, unsigned short* __restrict__ out_bf,
    float* __restrict__ out_f32) {
    int row = blockIdx.x;
    int t = threadIdx.x;
    size_t o4 = (size_t)row * 256 + t;
    float4 v  = ((const float4*)x_res)[o4];
    float4 a0 = ((const float4*)p0)[o4];
    float4 a1 = ((const float4*)p1)[o4];
    float4 a2 = ((const float4*)p2)[o4];
    float4 a3 = ((const float4*)p3)[o4];
    v.x += (a0.x + a1.x) + (a2.x + a3.x);
    v.y += (a0.y + a1.y) + (a2.y + a3.y);
    v.z += (a0.z + a1.z) + (a2.z + a3.z);
    v.w += (a0.w + a1.w) + (a2.w + a3.w);
    ((float4*)x_res)[o4] = v;
    float s  = v.x + v.y + v.z + v.w;
    float ss = v.x*v.x + v.y*v.y + v.z*v.z + v.w*v.w;
    for (int o = 32; o; o >>= 1) { s += __shfl_xor(s, o); ss += __shfl_xor(ss, o); }
    __shared__ float red[8];
    int wv = t >> 6;
    if ((t & 63) == 0) { red[wv * 2] = s; red[wv * 2 + 1] = ss; }
    __syncthreads();
    s  = red[0] + red[2] + red[4] + red[6];
    ss = red[1] + red[3] + red[5] + red[7];
    float mu = s * (1.f / DMODEL);
    float rstd = rsqrtf(ss * (1.f / DMODEL) - mu * mu + 1e-5f);
    float4 gv = ((const float4*)g)[t];
    float4 bv = ((const float4*)b)[t];
    float o0 = (v.x - mu) * rstd * gv.x + bv.x;
    float o1 = (v.y - mu) * rstd * gv.y + bv.y;
    float o2 = (v.z - mu) * rstd * gv.z + bv.z;
    float o3 = (v.w - mu) * rstd * gv.w + bv.w;
    if (out_f32) {
        ((float4*)out_f32)[o4] = make_float4(o0, o1, o2, o3);
    } else {
        ((ushort4*)out_bf)[o4] = make_ushort4(f2bf(o0), f2bf(o1), f2bf(o2), f2bf(o3));
    }
}

// ---------------- GEMM: C[M,N] = A[M,K](bf16) * B[N,K]^T(bf16) ----------------
// 128x64 tile, 4 waves, depth-3 LDS pipeline (36 KB -> 4 blocks/CU).
// Modes: 0 = f32 store into partial z (Cv + z*M*N); 2 = bf16 store.
// R6 note: atomic accumulate across split-K XCDs was a 4x regression.
// R8 note: grid-barrier scan fusion was a 10x regression (spin storm on one line).
#define BKG 32
__global__ __launch_bounds__(256) void gemm64(
    const unsigned short* __restrict__ A, const unsigned short* __restrict__ B,
    void* __restrict__ Cv, int M, int N, int K, int Nb, int mode) {
    __shared__ __attribute__((aligned(16))) unsigned short As[3][128 * BKG];
    __shared__ __attribute__((aligned(16))) unsigned short Bs[3][64 * BKG];
    int m0 = blockIdx.y * 128, n0 = blockIdx.x * 64;
    int Klocal = K / gridDim.z;
    int kstart = blockIdx.z * Klocal;
    int t = threadIdx.x;
    int lane = t & 63, w = t >> 6;
    int tr = lane & 15, quad = lane >> 4;
    int r_l = lane >> 2;
    int q_l = (lane & 3) ^ ((lane >> 3) & 3);      // swizzled 16B-unit
    int col_l = q_l * 8;

    float4v acc[2][4];
    for (int mi = 0; mi < 2; ++mi)
        for (int ni = 0; ni < 4; ++ni)
            acc[mi][ni] = (float4v){0.f, 0.f, 0.f, 0.f};

    auto stage = [&](int kt, int buf) {
        int kbase = kstart + kt * BKG;
#pragma unroll
        for (int j = 0; j < 2; ++j) {
            int c = w * 2 + j;
            const unsigned short* ga = A + (size_t)(m0 + c * 16 + r_l) * K + kbase + col_l;
            __builtin_amdgcn_global_load_lds(
                (const __attribute__((address_space(1))) void*)ga,
                (__attribute__((address_space(3))) void*)(&As[buf][c * 512]),
                16, 0, 0);
        }
        int brow = n0 + w * 16 + r_l;
        if (brow >= Nb) brow = Nb - 1;
        const unsigned short* gb = B + (size_t)brow * K + kbase + col_l;
        __builtin_amdgcn_global_load_lds(
            (const __attribute__((address_space(1))) void*)gb,
            (__attribute__((address_space(3))) void*)(&Bs[buf][w * 512]),
            16, 0, 0);
    };

    int KT = Klocal / BKG;
    stage(0, 0);
    if (KT > 1) stage(1, 1);
    int u_off = (tr * 4 + (quad ^ ((tr >> 1) & 3))) * 8;
    for (int kt = 0; kt < KT; ++kt) {
        int cur = kt % 3;
        if (kt + 2 < KT) stage(kt + 2, (kt + 2) % 3);
        asm volatile("" ::: "memory");
        int nleft = KT - kt - 1;
        if (nleft >= 2)      __builtin_amdgcn_s_waitcnt(0x0F76);  // vmcnt(6)
        else if (nleft == 1) __builtin_amdgcn_s_waitcnt(0x0F73);  // vmcnt(3)
        else                 __builtin_amdgcn_s_waitcnt(0x0F70);  // vmcnt(0)
        __builtin_amdgcn_s_barrier();
        asm volatile("" ::: "memory");
        short8 af[2], bfr[4];
#pragma unroll
        for (int i = 0; i < 2; ++i)
            af[i] = *(const short8*)(&As[cur][(w * 2 + i) * 512 + u_off]);
#pragma unroll
        for (int i = 0; i < 4; ++i)
            bfr[i] = *(const short8*)(&Bs[cur][i * 512 + u_off]);
#pragma unroll
        for (int mi = 0; mi < 2; ++mi)
#pragma unroll
            for (int ni = 0; ni < 4; ++ni)
                acc[mi][ni] = __builtin_amdgcn_mfma_f32_16x16x32_bf16(
                    af[mi], bfr[ni], acc[mi][ni], 0, 0, 0);
        asm volatile("" ::: "memory");
        __builtin_amdgcn_s_barrier();
        asm volatile("" ::: "memory");
    }
    // C/D layout (m89-verified): col = lane&15, row = (lane>>4)*4 + reg
    size_t zoff = (size_t)blockIdx.z * M * N;
    for (int mi = 0; mi < 2; ++mi)
        for (int ni = 0; ni < 4; ++ni) {
            int col = n0 + ni * 16 + tr;
            int rowb = m0 + w * 32 + mi * 16 + quad * 4;
            for (int r = 0; r < 4; ++r) {
                size_t off = (size_t)(rowb + r) * N + col;
                float val = acc[mi][ni][r];
                if (mode == 0) {
                    ((float*)Cv)[zoff + off] = val;
                } else {
                    ((unsigned short*)Cv)[off] = f2bf(val);
                }
            }
        }
}

// ---------------- reduce 8 xp partials -> dtA(bf16) + compact BC(f32) ----------------
__global__ __launch_bounds__(256) void reduce_xp(
    const float* __restrict__ part, unsigned short* __restrict__ dtA,
    float* __restrict__ BC) {
    int i = blockIdx.x * 256 + threadIdx.x;      // NTOK*128
    int row = i >> 7, col = i & 127;
    float s = 0.f;
#pragma unroll
    for (int z = 0; z < XSPK; ++z)
        s += part[(size_t)z * NTOK * XDS + i];
    if (col < 64) dtA[row * 64 + col] = f2bf(s);
    else if (col < 96) BC[row * 32 + (col - 64)] = s;
}

// ---------------- causal depthwise conv(4) + bias + silu; bf16 -> bf16, 8 ch/thread ----------------
__global__ __launch_bounds__(256) void conv_silu(
    const unsigned short* __restrict__ xz, const float* __restrict__ cw,
    const float* __restrict__ cb, unsigned short* __restrict__ xm_bf) {
    int i = blockIdx.x * 256 + threadIdx.x;   // NTOK * DINNER/8
    int c8 = i & (DINNER / 8 - 1);
    int tk = i >> 8;
    int l = tk & (SEQL - 1);
    int c = c8 * 8;
    const unsigned short* base = xz + (size_t)tk * (2 * DINNER) + c;
    short8 r3 = {0,0,0,0,0,0,0,0}, r2 = {0,0,0,0,0,0,0,0}, r1 = {0,0,0,0,0,0,0,0};
    if (l >= 3) r3 = *(const short8*)(base - 3 * 2 * DINNER);
    if (l >= 2) r2 = *(const short8*)(base - 2 * 2 * DINNER);
    if (l >= 1) r1 = *(const short8*)(base - 1 * 2 * DINNER);
    short8 r0 = *(const short8*)(base);
    short8 out;
#pragma unroll
    for (int j = 0; j < 8; ++j) {
        float4 wv = ((const float4*)cw)[c + j];
        float acc = cb[c + j]
            + bf2f((unsigned short)r3[j]) * wv.x
            + bf2f((unsigned short)r2[j]) * wv.y
            + bf2f((unsigned short)r1[j]) * wv.z
            + bf2f((unsigned short)r0[j]) * wv.w;
        float sv = acc / (1.f + expf(-acc));
        out[j] = (short)f2bf(sv);
    }
    *(short8*)(xm_bf + (size_t)tk * DINNER + c) = out;
}

// ---------------- scan phase A: dt-dot fused + local recurrence -> h_end, S ----------------
// dt[token][c] = softplus(dtA[token]Â·wdtT[:,c] + dtb[c]); dtA rows staged in LDS,
// w column held as 32 packed-bf16 uints (pair-interleaved layout from cvt_dtT).
__global__ __launch_bounds__(256) void scan_a(
    const unsigned short* __restrict__ dtA, const unsigned short* __restrict__ wdtT,
    const float* __restrict__ dtb, const unsigned short* __restrict__ xm_bf,
    const float* __restrict__ BC, const float* __restrict__ A_log,
    float* __restrict__ h_end, float* __restrict__ S_chunk) {
    int bid = blockIdx.x;                 // GCH*2*8 = 1024
    int g = bid >> 4, b = (bid >> 3) & 1, cbk = bid & 7;
    int c = cbk * 256 + threadIdx.x;
    int rowbase = b * SEQL + g * LC;
    __shared__ float Bsh[LC][16];
    __shared__ unsigned dtash[LC * 32];   // LC rows x 64 bf16
    {
        int li = threadIdx.x >> 4, s = threadIdx.x & 15;
        Bsh[li][s] = BC[((size_t)(rowbase + li)) * 32 + s];
        ((uint2*)dtash)[threadIdx.x] =
            ((const uint2*)(dtA + (size_t)rowbase * 64))[threadIdx.x];
    }
    __syncthreads();
    unsigned wp[32];
#pragma unroll
    for (int r2 = 0; r2 < 32; ++r2)
        wp[r2] = ((const unsigned*)wdtT)[(size_t)r2 * DINNER + c];
    float dbias = dtb[c];
    float a_l2[16], h[16];
#pragma unroll
    for (int s = 0; s < 16; ++s) {
        a_l2[s] = -expf(A_log[c * 16 + s]) * 1.44269504f;
        h[s] = 0.f;
    }
    float S = 0.f;
    for (int i = 0; i < LC; ++i) {
        float acc = dbias;
#pragma unroll
        for (int r2 = 0; r2 < 32; ++r2) {
            unsigned dv = dtash[i * 32 + r2];
            acc += bflo(dv) * bflo(wp[r2]) + bfhi(dv) * bfhi(wp[r2]);
        }
        float dtv = (acc > 15.f) ? acc : log1pf(expf(acc));
        S += dtv;
        size_t off = (size_t)(rowbase + i) * DINNER + c;
        float u = bf2f(xm_bf[off]);
        float bu = dtv * u;
#pragma unroll
        for (int s = 0; s < 16; ++s) {
            float dA = exp2f(dtv * a_l2[s]);
            h[s] = dA * h[s] + Bsh[i][s] * bu;
        }
    }
    int gb = g * 2 + b;
#pragma unroll
    for (int s = 0; s < 16; ++s)
        h_end[((size_t)gb * 16 + s) * DINNER + c] = h[s];
    S_chunk[(size_t)gb * DINNER + c] = S;
}

// ---------------- scan phase B: combine chunks -> h_in per chunk ----------------
__global__ __launch_bounds__(256) void scan_b(
    const float* __restrict__ A_log, const float* __restrict__ S_chunk,
    const float* __restrict__ h_end, float* __restrict__ h_in) {
    int idx = blockIdx.x * 256 + threadIdx.x;   // 2*16*2048 = 65536
    int c = idx & (DINNER - 1);
    int s = (idx >> 11) & 15;
    int b = idx >> 15;
    float a_l2 = -expf(A_log[c * 16 + s]) * 1.44269504f;
    float h = 0.f;
    for (int g = 0; g < GCH; ++g) {
        int gb = g * 2 + b;
        h_in[((size_t)gb * 16 + s) * DINNER + c] = h;
        float P = exp2f(a_l2 * S_chunk[(size_t)gb * DINNER + c]);
        h = P * h + h_end[((size_t)gb * 16 + s) * DINNER + c];
    }
}

// ---------------- scan phase C: dt-dot fused + seeded recurrence -> y ----------------
__global__ __launch_bounds__(256) void scan_c(
    const unsigned short* __restrict__ dtA, const unsigned short* __restrict__ wdtT,
    const float* __restrict__ dtb, const unsigned short* __restrict__ xm_bf,
    const float* __restrict__ BC, const float* __restrict__ A_log,
    const float* __restrict__ D_skip, const unsigned short* __restrict__ xz,
    const float* __restrict__ h_in, unsigned short* __restrict__ y_bf) {
    int bid = blockIdx.x;                 // 1024
    int g = bid >> 4, b = (bid >> 3) & 1, cbk = bid & 7;
    int c = cbk * 256 + threadIdx.x;
    int rowbase = b * SEQL + g * LC;
    __shared__ float BCsh[LC][32];
    __shared__ unsigned dtash[LC * 32];
    for (int r = 0; r < 2; ++r) {
        int e = threadIdx.x + r * 256;
        int li = e >> 5, s = e & 31;
        BCsh[li][s] = BC[((size_t)(rowbase + li)) * 32 + s];
    }
    ((uint2*)dtash)[threadIdx.x] =
        ((const uint2*)(dtA + (size_t)rowbase * 64))[threadIdx.x];
    __syncthreads();
    unsigned wp[32];
#pragma unroll
    for (int r2 = 0; r2 < 32; ++r2)
        wp[r2] = ((const unsigned*)wdtT)[(size_t)r2 * DINNER + c];
    float dbias = dtb[c];
    int gb = g * 2 + b;
    float a_l2[16], h[16];
#pragma unroll
    for (int s = 0; s < 16; ++s) {
        a_l2[s] = -expf(A_log[c * 16 + s]) * 1.44269504f;
        h[s] = h_in[((size_t)gb * 16 + s) * DINNER + c];
    }
    float dsk = D_skip[c];
    for (int i = 0; i < LC; ++i) {
        float acc = dbias;
#pragma unroll
        for (int r2 = 0; r2 < 32; ++r2) {
            unsigned dv = dtash[i * 32 + r2];
            acc += bflo(dv) * bflo(wp[r2]) + bfhi(dv) * bfhi(wp[r2]);
        }
        float dtv = (acc > 15.f) ? acc : log1pf(expf(acc));
        size_t off = (size_t)(rowbase + i) * DINNER + c;
        float u = bf2f(xm_bf[off]);
        float bu = dtv * u;
        float y = 0.f;
#pragma unroll
        for (int s = 0; s < 16; ++s) {
            float dA = exp2f(dtv * a_l2[s]);
            h[s] = dA * h[s] + BCsh[i][s] * bu;
            y += h[s] * BCsh[i][16 + s];
        }
        y += u * dsk;
        float zv = bf2f(xz[(size_t)(rowbase + i) * (2 * DINNER) + DINNER + c]);
        y *= zv / (1.f + expf(-zv));
        y_bf[off] = f2bf(y);
    }
}

extern "C" void kernel_launch(void* const* d_in, const int* in_sizes, int n_in,
                              void* d_out, int out_size, void* d_ws, size_t ws_size,
                              hipStream_t stream) {
    const float* x_in   = (const float*)d_in[0];
    const float* in_w   = (const float*)d_in[1];
    const float* conv_w = (const float*)d_in[2];
    const float* conv_b = (const float*)d_in[3];
    const float* xp_w   = (const float*)d_in[4];
    const float* dt_w   = (const float*)d_in[5];
    const float* dt_b   = (const float*)d_in[6];
    const float* A_logp = (const float*)d_in[7];
    const float* Dsk    = (const float*)d_in[8];
    const float* out_w  = (const float*)d_in[9];
    const float* ln_g   = (const float*)d_in[10];
    const float* ln_b   = (const float*)d_in[11];
    float* outp = (float*)d_out;

    char* p = (char*)d_ws;
    auto alloc = [&](size_t bytes) {
        void* r = (void*)p;
        p += (bytes + 255) & ~(size_t)255;
        return r;
    };
    float* x_res  = (float*)alloc((size_t)NTOK * DMODEL * 4);
    unsigned short* xn_bf = (unsigned short*)alloc((size_t)NTOK * DMODEL * 2);
    unsigned short* xz_bf = (unsigned short*)alloc((size_t)NTOK * 2 * DINNER * 2);
    unsigned short* xm_bf = (unsigned short*)alloc((size_t)NTOK * DINNER * 2);
    float* xp_part = (float*)alloc((size_t)XSPK * NTOK * XDS * 4);
    float* out_part = (float*)alloc((size_t)4 * NTOK * DMODEL * 4);
    float* BC     = (float*)alloc((size_t)NTOK * 32 * 4);
    unsigned short* dtA_bf = (unsigned short*)alloc((size_t)NTOK * DTRANK * 2);
    unsigned short* y_bf = (unsigned short*)alloc((size_t)NTOK * DINNER * 2);
    float* h_end  = (float*)alloc((size_t)GCH * 2 * 16 * DINNER * 4);
    float* h_in   = (float*)alloc((size_t)GCH * 2 * 16 * DINNER * 4);
    float* S_chunk = (float*)alloc((size_t)GCH * 2 * DINNER * 4);
    int n_inw  = 4 * 2 * DINNER * DMODEL;
    int n_xpw  = 4 * 96 * DINNER;
    int n_dtw  = 4 * DINNER * DTRANK;
    int n_outw = 4 * DMODEL * DINNER;
    unsigned short* wbf_in  = (unsigned short*)alloc((size_t)n_inw * 2);
    unsigned short* wbf_xp  = (unsigned short*)alloc((size_t)n_xpw * 2);
    unsigned short* wbf_dtT = (unsigned short*)alloc((size_t)n_dtw * 2);
    unsigned short* wbf_out = (unsigned short*)alloc((size_t)n_outw * 2);

    // counts in 16-elem groups (all sizes divisible by 16)
    int c0 = n_inw / 16;
    int c1 = c0 + n_xpw / 16;
    int c2 = c1 + n_outw / 16;
    f32_to_bf16_3<<<(c2 + 255) / 256, 256, 0, stream>>>(
        in_w, wbf_in, c0, xp_w, wbf_xp, c1, out_w, wbf_out, c2);
    cvt_dtT<<<n_dtw / 256, 256, 0, stream>>>(dt_w, wbf_dtT);

    // LN also copies x into x_res (replaces the memcpy)
    ln_kernel<<<NTOK, 256, 0, stream>>>(x_in, x_res, ln_g, ln_b, xn_bf);

    for (int L = 0; L < 4; ++L) {
        const unsigned short* w_in  = wbf_in  + (size_t)L * 2 * DINNER * DMODEL;
        const float*          w_cv  = conv_w  + (size_t)L * DINNER * 4;
        const float*          b_cv  = conv_b  + (size_t)L * DINNER;
        const unsigned short* w_xp  = wbf_xp  + (size_t)L * 96 * DINNER;
        const unsigned short* w_dtT = wbf_dtT + (size_t)L * 64 * DINNER;
        const float*          b_dt  = dt_b    + (size_t)L * DINNER;
        const float*          al    = A_logp  + (size_t)L * DINNER * DSTATE;
        const float*          dskl  = Dsk     + (size_t)L * DINNER;
        const unsigned short* w_out = wbf_out + (size_t)L * DMODEL * DINNER;

        // in_proj: [2048 x 4096 x 1024] -> bf16, 128x64 tile, 1024 blocks (4/CU)
        gemm64<<<dim3(64, 16, 1), 256, 0, stream>>>(
            xn_bf, w_in, xz_bf, NTOK, 2 * DINNER, DMODEL, 2 * DINNER, 2);
        conv_silu<<<NTOK * (DINNER / 8) / 256, 256, 0, stream>>>(xz_bf, w_cv, b_cv, xm_bf);
        // x_proj: [2048 x 128(96) x 2048], split-K 8 -> f32 partials
        gemm64<<<dim3(2, 16, XSPK), 256, 0, stream>>>(
            xm_bf, w_xp, xp_part, NTOK, XDS, DINNER, 96, 0);
        reduce_xp<<<NTOK * XDS / 256, 256, 0, stream>>>(xp_part, dtA_bf, BC);
        // scan (dt_proj fused into phases A and C as a dot-64 per channel)
        scan_a<<<GCH * 16, 256, 0, stream>>>(dtA_bf, w_dtT, b_dt, xm_bf, BC, al,
                                             h_end, S_chunk);
        scan_b<<<2 * 16 * DINNER / 256, 256, 0, stream>>>(al, S_chunk, h_end, h_in);
        scan_c<<<GCH * 16, 256, 0, stream>>>(dtA_bf, w_dtT, b_dt, xm_bf, BC, al,
                                             dskl, xz_bf, h_in, y_bf);
        // out_proj: [2048 x 1024 x 2048], split-K 4 -> 1024 blocks (4/CU), KT=16
        gemm64<<<dim3(16, 16, 4), 256, 0, stream>>>(
            y_bf, w_out, out_part, NTOK, DMODEL, DINNER, DMODEL, 0);
        // fused: x_res += p0+p1+p2+p3; LN -> next xn (bf16) or final out (f32)
        residual_ln<<<NTOK, 256, 0, stream>>>(
            x_res, out_part, out_part + (size_t)NTOK * DMODEL,
            out_part + (size_t)2 * NTOK * DMODEL, out_part + (size_t)3 * NTOK * DMODEL,
            ln_g, ln_b, (L < 3) ? xn_bf : nullptr, (L < 3) ? nullptr : outp);
    }
}

// Round 10
// 898.349 us; speedup vs baseline: 2.8007x; 1.0709x over previous
//
#include <hip/hip_runtime.h>

#define NTOK 2048      // BATCH*SEQ
#define SEQL 1024
#define DMODEL 1024
#define DINNER 2048
#define DSTATE 16
#define DTRANK 64
#define GCH 128        // scan chunks (R10: 64 -> 128, latency-bound scan wants TLP)
#define LC 8           // steps per chunk (16 -> 8)
#define XDS 128        // padded xp-GEMM N (96 -> 128)
#define XSPK 8         // x_proj split-K factor (proven config)

typedef __attribute__((ext_vector_type(8))) short short8;
typedef __attribute__((ext_vector_type(4))) float float4v;

__device__ __forceinline__ unsigned short f2bf(float f) {
    unsigned u = __float_as_uint(f);
    unsigned r = u + 0x7FFFu + ((u >> 16) & 1u);
    return (unsigned short)(r >> 16);
}
__device__ __forceinline__ float bf2f(unsigned short h) {
    return __uint_as_float(((unsigned)h) << 16);
}

// ---------------- fused f32 -> bf16 weight conversion, 16 elems/thread ----------------
__global__ __launch_bounds__(256) void f32_to_bf16_4(
    const float* __restrict__ s0, unsigned short* __restrict__ d0, int c0,
    const float* __restrict__ s1, unsigned short* __restrict__ d1, int c1,
    const float* __restrict__ s2, unsigned short* __restrict__ d2, int c2,
    const float* __restrict__ s3, unsigned short* __restrict__ d3, int c3) {
    int i = blockIdx.x * 256 + threadIdx.x;      // i indexes 16-elem groups
    if (i >= c3) return;
    const float* s; unsigned short* dd; int j;
    if (i < c0)      { s = s0; dd = d0; j = i; }
    else if (i < c1) { s = s1; dd = d1; j = i - c0; }
    else if (i < c2) { s = s2; dd = d2; j = i - c1; }
    else             { s = s3; dd = d3; j = i - c2; }
    float4 a = ((const float4*)s)[4 * j];
    float4 b = ((const float4*)s)[4 * j + 1];
    float4 c = ((const float4*)s)[4 * j + 2];
    float4 d = ((const float4*)s)[4 * j + 3];
    uint4 v0, v1;
    v0.x = (unsigned)f2bf(a.x) | ((unsigned)f2bf(a.y) << 16);
    v0.y = (unsigned)f2bf(a.z) | ((unsigned)f2bf(a.w) << 16);
    v0.z = (unsigned)f2bf(b.x) | ((unsigned)f2bf(b.y) << 16);
    v0.w = (unsigned)f2bf(b.z) | ((unsigned)f2bf(b.w) << 16);
    v1.x = (unsigned)f2bf(c.x) | ((unsigned)f2bf(c.y) << 16);
    v1.y = (unsigned)f2bf(c.z) | ((unsigned)f2bf(c.w) << 16);
    v1.z = (unsigned)f2bf(d.x) | ((unsigned)f2bf(d.y) << 16);
    v1.w = (unsigned)f2bf(d.z) | ((unsigned)f2bf(d.w) << 16);
    ((uint4*)dd)[2 * j]     = v0;
    ((uint4*)dd)[2 * j + 1] = v1;
}

// ---------------- LayerNorm (prologue): f32 in -> bf16 out, also copies x into x_res ----------------
__global__ __launch_bounds__(256) void ln_kernel(
    const float* __restrict__ x, float* __restrict__ x_copy,
    const float* __restrict__ g, const float* __restrict__ b,
    unsigned short* __restrict__ out_bf) {
    int row = blockIdx.x;
    int t = threadIdx.x;
    float4 v = ((const float4*)(x + (size_t)row * DMODEL))[t];
    ((float4*)(x_copy + (size_t)row * DMODEL))[t] = v;
    float s  = v.x + v.y + v.z + v.w;
    float ss = v.x*v.x + v.y*v.y + v.z*v.z + v.w*v.w;
    for (int o = 32; o; o >>= 1) { s += __shfl_xor(s, o); ss += __shfl_xor(ss, o); }
    __shared__ float red[8];
    int wv = t >> 6;
    if ((t & 63) == 0) { red[wv * 2] = s; red[wv * 2 + 1] = ss; }
    __syncthreads();
    s  = red[0] + red[2] + red[4] + red[6];
    ss = red[1] + red[3] + red[5] + red[7];
    float mu = s * (1.f / DMODEL);
    float rstd = rsqrtf(ss * (1.f / DMODEL) - mu * mu + 1e-5f);
    float4 gv = ((const float4*)g)[t];
    float4 bv = ((const float4*)b)[t];
    ((ushort4*)out_bf)[row * 256 + t] = make_ushort4(
        f2bf((v.x - mu) * rstd * gv.x + bv.x),
        f2bf((v.y - mu) * rstd * gv.y + bv.y),
        f2bf((v.z - mu) * rstd * gv.z + bv.z),
        f2bf((v.w - mu) * rstd * gv.w + bv.w));
}

// ---------------- fused: x_res += p0+p1+p2+p3 ; LN(x_res) -> bf16 (or f32 final) ----------------
__global__ __launch_bounds__(256) void residual_ln(
    float* __restrict__ x_res, const float* __restrict__ p0,
    const float* __restrict__ p1, const float* __restrict__ p2,
    const float* __restrict__ p3, const float* __restrict__ g,
    const float* __restrict__ b, unsigned short* __restrict__ out_bf,
    float* __restrict__ out_f32) {
    int row = blockIdx.x;
    int t = threadIdx.x;
    size_t o4 = (size_t)row * 256 + t;
    float4 v  = ((const float4*)x_res)[o4];
    float4 a0 = ((const float4*)p0)[o4];
    float4 a1 = ((const float4*)p1)[o4];
    float4 a2 = ((const float4*)p2)[o4];
    float4 a3 = ((const float4*)p3)[o4];
    v.x += (a0.x + a1.x) + (a2.x + a3.x);
    v.y += (a0.y + a1.y) + (a2.y + a3.y);
    v.z += (a0.z + a1.z) + (a2.z + a3.z);
    v.w += (a0.w + a1.w) + (a2.w + a3.w);
    ((float4*)x_res)[o4] = v;
    float s  = v.x + v.y + v.z + v.w;
    float ss = v.x*v.x + v.y*v.y + v.z*v.z + v.w*v.w;
    for (int o = 32; o; o >>= 1) { s += __shfl_xor(s, o); ss += __shfl_xor(ss, o); }
    __shared__ float red[8];
    int wv = t >> 6;
    if ((t & 63) == 0) { red[wv * 2] = s; red[wv * 2 + 1] = ss; }
    __syncthreads();
    s  = red[0] + red[2] + red[4] + red[6];
    ss = red[1] + red[3] + red[5] + red[7];
    float mu = s * (1.f / DMODEL);
    float rstd = rsqrtf(ss * (1.f / DMODEL) - mu * mu + 1e-5f);
    float4 gv = ((const float4*)g)[t];
    float4 bv = ((const float4*)b)[t];
    float o0 = (v.x - mu) * rstd * gv.x + bv.x;
    float o1 = (v.y - mu) * rstd * gv.y + bv.y;
    float o2 = (v.z - mu) * rstd * gv.z + bv.z;
    float o3 = (v.w - mu) * rstd * gv.w + bv.w;
    if (out_f32) {
        ((float4*)out_f32)[o4] = make_float4(o0, o1, o2, o3);
    } else {
        ((ushort4*)out_bf)[o4] = make_ushort4(f2bf(o0), f2bf(o1), f2bf(o2), f2bf(o3));
    }
}

// ---------------- GEMM: C[M,N] = A[M,K](bf16) * B[N,K]^T(bf16) ----------------
// 128x64 tile, 4 waves, depth-3 LDS pipeline (36 KB -> 4 blocks/CU).
// Modes: 0 = f32 store into partial z (Cv + z*M*N); 2 = bf16 store;
// 3 = bf16 store of softplus(acc + bias[col]).
// R6: atomic split-K accumulate = 4x regression. R8: grid-barrier fusion = 10x.
// R9: dt_proj on VALU inside scan = 2.3x regression on scan kernels. Keep MFMA.
#define BKG 32
__global__ __launch_bounds__(256) void gemm64(
    const unsigned short* __restrict__ A, const unsigned short* __restrict__ B,
    void* __restrict__ Cv, const float* __restrict__ bias,
    int M, int N, int K, int Nb, int mode) {
    __shared__ __attribute__((aligned(16))) unsigned short As[3][128 * BKG];
    __shared__ __attribute__((aligned(16))) unsigned short Bs[3][64 * BKG];
    int m0 = blockIdx.y * 128, n0 = blockIdx.x * 64;
    int Klocal = K / gridDim.z;
    int kstart = blockIdx.z * Klocal;
    int t = threadIdx.x;
    int lane = t & 63, w = t >> 6;
    int tr = lane & 15, quad = lane >> 4;
    int r_l = lane >> 2;
    int q_l = (lane & 3) ^ ((lane >> 3) & 3);      // swizzled 16B-unit
    int col_l = q_l * 8;

    float4v acc[2][4];
    for (int mi = 0; mi < 2; ++mi)
        for (int ni = 0; ni < 4; ++ni)
            acc[mi][ni] = (float4v){0.f, 0.f, 0.f, 0.f};

    auto stage = [&](int kt, int buf) {
        int kbase = kstart + kt * BKG;
#pragma unroll
        for (int j = 0; j < 2; ++j) {
            int c = w * 2 + j;
            const unsigned short* ga = A + (size_t)(m0 + c * 16 + r_l) * K + kbase + col_l;
            __builtin_amdgcn_global_load_lds(
                (const __attribute__((address_space(1))) void*)ga,
                (__attribute__((address_space(3))) void*)(&As[buf][c * 512]),
                16, 0, 0);
        }
        int brow = n0 + w * 16 + r_l;
        if (brow >= Nb) brow = Nb - 1;
        const unsigned short* gb = B + (size_t)brow * K + kbase + col_l;
        __builtin_amdgcn_global_load_lds(
            (const __attribute__((address_space(1))) void*)gb,
            (__attribute__((address_space(3))) void*)(&Bs[buf][w * 512]),
            16, 0, 0);
    };

    int KT = Klocal / BKG;
    stage(0, 0);
    if (KT > 1) stage(1, 1);
    int u_off = (tr * 4 + (quad ^ ((tr >> 1) & 3))) * 8;
    for (int kt = 0; kt < KT; ++kt) {
        int cur = kt % 3;
        if (kt + 2 < KT) stage(kt + 2, (kt + 2) % 3);
        asm volatile("" ::: "memory");
        int nleft = KT - kt - 1;
        if (nleft >= 2)      __builtin_amdgcn_s_waitcnt(0x0F76);  // vmcnt(6)
        else if (nleft == 1) __builtin_amdgcn_s_waitcnt(0x0F73);  // vmcnt(3)
        else                 __builtin_amdgcn_s_waitcnt(0x0F70);  // vmcnt(0)
        __builtin_amdgcn_s_barrier();
        asm volatile("" ::: "memory");
        short8 af[2], bfr[4];
#pragma unroll
        for (int i = 0; i < 2; ++i)
            af[i] = *(const short8*)(&As[cur][(w * 2 + i) * 512 + u_off]);
#pragma unroll
        for (int i = 0; i < 4; ++i)
            bfr[i] = *(const short8*)(&Bs[cur][i * 512 + u_off]);
#pragma unroll
        for (int mi = 0; mi < 2; ++mi)
#pragma unroll
            for (int ni = 0; ni < 4; ++ni)
                acc[mi][ni] = __builtin_amdgcn_mfma_f32_16x16x32_bf16(
                    af[mi], bfr[ni], acc[mi][ni], 0, 0, 0);
        asm volatile("" ::: "memory");
        __builtin_amdgcn_s_barrier();
        asm volatile("" ::: "memory");
    }
    // C/D layout (m89-verified): col = lane&15, row = (lane>>4)*4 + reg
    size_t zoff = (size_t)blockIdx.z * M * N;
    for (int mi = 0; mi < 2; ++mi)
        for (int ni = 0; ni < 4; ++ni) {
            int col = n0 + ni * 16 + tr;
            int rowb = m0 + w * 32 + mi * 16 + quad * 4;
            for (int r = 0; r < 4; ++r) {
                size_t off = (size_t)(rowb + r) * N + col;
                float val = acc[mi][ni][r];
                if (mode == 0) {
                    ((float*)Cv)[zoff + off] = val;
                } else if (mode == 2) {
                    ((unsigned short*)Cv)[off] = f2bf(val);
                } else {
                    float v2 = val + bias[col];
                    float sp = (v2 > 15.f) ? v2 : log1pf(expf(v2));
                    ((unsigned short*)Cv)[off] = f2bf(sp);
                }
            }
        }
}

// ---------------- reduce 8 xp partials -> dtA(bf16) + compact BC(f32) ----------------
__global__ __launch_bounds__(256) void reduce_xp(
    const float* __restrict__ part, unsigned short* __restrict__ dtA,
    float* __restrict__ BC) {
    int i = blockIdx.x * 256 + threadIdx.x;      // NTOK*128
    int row = i >> 7, col = i & 127;
    float s = 0.f;
#pragma unroll
    for (int z = 0; z < XSPK; ++z)
        s += part[(size_t)z * NTOK * XDS + i];
    if (col < 64) dtA[row * 64 + col] = f2bf(s);
    else if (col < 96) BC[row * 32 + (col - 64)] = s;
}

// ---------------- causal depthwise conv(4) + bias + silu; bf16 -> bf16, 8 ch/thread ----------------
__global__ __launch_bounds__(256) void conv_silu(
    const unsigned short* __restrict__ xz, const float* __restrict__ cw,
    const float* __restrict__ cb, unsigned short* __restrict__ xm_bf) {
    int i = blockIdx.x * 256 + threadIdx.x;   // NTOK * DINNER/8
    int c8 = i & (DINNER / 8 - 1);
    int tk = i >> 8;
    int l = tk & (SEQL - 1);
    int c = c8 * 8;
    const unsigned short* base = xz + (size_t)tk * (2 * DINNER) + c;
    short8 r3 = {0,0,0,0,0,0,0,0}, r2 = {0,0,0,0,0,0,0,0}, r1 = {0,0,0,0,0,0,0,0};
    if (l >= 3) r3 = *(const short8*)(base - 3 * 2 * DINNER);
    if (l >= 2) r2 = *(const short8*)(base - 2 * 2 * DINNER);
    if (l >= 1) r1 = *(const short8*)(base - 1 * 2 * DINNER);
    short8 r0 = *(const short8*)(base);
    short8 out;
#pragma unroll
    for (int j = 0; j < 8; ++j) {
        float4 wv = ((const float4*)cw)[c + j];
        float acc = cb[c + j]
            + bf2f((unsigned short)r3[j]) * wv.x
            + bf2f((unsigned short)r2[j]) * wv.y
            + bf2f((unsigned short)r1[j]) * wv.z
            + bf2f((unsigned short)r0[j]) * wv.w;
        float sv = acc / (1.f + expf(-acc));
        out[j] = (short)f2bf(sv);
    }
    *(short8*)(xm_bf + (size_t)tk * DINNER + c) = out;
}

// ---------------- scan phase A: local recurrence -> h_end, S ----------------
// GCH=128/LC=8: 2048 blocks (8/CU) with 8 serial steps each — TLP for the
// latency-bound regime (R9 counters: 444 GB/s, 24% occ => latency, not BW).
__global__ __launch_bounds__(256) void scan_a(
    const unsigned short* __restrict__ dt_bf, const unsigned short* __restrict__ xm_bf,
    const float* __restrict__ BC, const float* __restrict__ A_log,
    float* __restrict__ h_end, float* __restrict__ S_chunk) {
    int bid = blockIdx.x;                 // GCH*2*8 = 2048
    int g = bid >> 4, b = (bid >> 3) & 1, cbk = bid & 7;
    int c = cbk * 256 + threadIdx.x;
    int rowbase = b * SEQL + g * LC;
    __shared__ float Bsh[LC][16];
    if (threadIdx.x < LC * 16) {
        int li = threadIdx.x >> 4, s = threadIdx.x & 15;
        Bsh[li][s] = BC[((size_t)(rowbase + li)) * 32 + s];
    }
    __syncthreads();
    float a_l2[16], h[16];
#pragma unroll
    for (int s = 0; s < 16; ++s) {
        a_l2[s] = -expf(A_log[c * 16 + s]) * 1.44269504f;
        h[s] = 0.f;
    }
    float S = 0.f;
    for (int i = 0; i < LC; ++i) {
        size_t off = (size_t)(rowbase + i) * DINNER + c;
        float dtv = bf2f(dt_bf[off]);
        S += dtv;
        float u = bf2f(xm_bf[off]);
        float bu = dtv * u;
#pragma unroll
        for (int s = 0; s < 16; ++s) {
            float dA = exp2f(dtv * a_l2[s]);
            h[s] = dA * h[s] + Bsh[i][s] * bu;
        }
    }
    int gb = g * 2 + b;
#pragma unroll
    for (int s = 0; s < 16; ++s)
        h_end[((size_t)gb * 16 + s) * DINNER + c] = h[s];
    S_chunk[(size_t)gb * DINNER + c] = S;
}

// ---------------- scan phase B: combine chunks -> h_in per chunk ----------------
__global__ __launch_bounds__(256) void scan_b(
    const float* __restrict__ A_log, const float* __restrict__ S_chunk,
    const float* __restrict__ h_end, float* __restrict__ h_in) {
    int idx = blockIdx.x * 256 + threadIdx.x;   // 2*16*2048 = 65536
    int c = idx & (DINNER - 1);
    int s = (idx >> 11) & 15;
    int b = idx >> 15;
    float a_l2 = -expf(A_log[c * 16 + s]) * 1.44269504f;
    float h = 0.f;
    for (int g = 0; g < GCH; ++g) {
        int gb = g * 2 + b;
        h_in[((size_t)gb * 16 + s) * DINNER + c] = h;
        float P = exp2f(a_l2 * S_chunk[(size_t)gb * DINNER + c]);
        h = P * h + h_end[((size_t)gb * 16 + s) * DINNER + c];
    }
}

// ---------------- scan phase C: seeded recurrence -> y ----------------
__global__ __launch_bounds__(256) void scan_c(
    const unsigned short* __restrict__ dt_bf, const unsigned short* __restrict__ xm_bf,
    const float* __restrict__ BC, const float* __restrict__ A_log,
    const float* __restrict__ D_skip, const unsigned short* __restrict__ xz,
    const float* __restrict__ h_in, unsigned short* __restrict__ y_bf) {
    int bid = blockIdx.x;                 // 2048
    int g = bid >> 4, b = (bid >> 3) & 1, cbk = bid & 7;
    int c = cbk * 256 + threadIdx.x;
    int rowbase = b * SEQL + g * LC;
    __shared__ float BCsh[LC][32];
    {
        int li = threadIdx.x >> 5, s = threadIdx.x & 31;   // 256 = 8 rows x 32
        BCsh[li][s] = BC[((size_t)(rowbase + li)) * 32 + s];
    }
    __syncthreads();
    int gb = g * 2 + b;
    float a_l2[16], h[16];
#pragma unroll
    for (int s = 0; s < 16; ++s) {
        a_l2[s] = -expf(A_log[c * 16 + s]) * 1.44269504f;
        h[s] = h_in[((size_t)gb * 16 + s) * DINNER + c];
    }
    float dsk = D_skip[c];
    for (int i = 0; i < LC; ++i) {
        size_t off = (size_t)(rowbase + i) * DINNER + c;
        float dtv = bf2f(dt_bf[off]);
        float u = bf2f(xm_bf[off]);
        float bu = dtv * u;
        float y = 0.f;
#pragma unroll
        for (int s = 0; s < 16; ++s) {
            float dA = exp2f(dtv * a_l2[s]);
            h[s] = dA * h[s] + BCsh[i][s] * bu;
            y += h[s] * BCsh[i][16 + s];
        }
        y += u * dsk;
        float zv = bf2f(xz[(size_t)(rowbase + i) * (2 * DINNER) + DINNER + c]);
        y *= zv / (1.f + expf(-zv));
        y_bf[off] = f2bf(y);
    }
}

extern "C" void kernel_launch(void* const* d_in, const int* in_sizes, int n_in,
                              void* d_out, int out_size, void* d_ws, size_t ws_size,
                              hipStream_t stream) {
    const float* x_in   = (const float*)d_in[0];
    const float* in_w   = (const float*)d_in[1];
    const float* conv_w = (const float*)d_in[2];
    const float* conv_b = (const float*)d_in[3];
    const float* xp_w   = (const float*)d_in[4];
    const float* dt_w   = (const float*)d_in[5];
    const float* dt_b   = (const float*)d_in[6];
    const float* A_logp = (const float*)d_in[7];
    const float* Dsk    = (const float*)d_in[8];
    const float* out_w  = (const float*)d_in[9];
    const float* ln_g   = (const float*)d_in[10];
    const float* ln_b   = (const float*)d_in[11];
    float* outp = (float*)d_out;

    char* p = (char*)d_ws;
    auto alloc = [&](size_t bytes) {
        void* r = (void*)p;
        p += (bytes + 255) & ~(size_t)255;
        return r;
    };
    float* x_res  = (float*)alloc((size_t)NTOK * DMODEL * 4);
    unsigned short* xn_bf = (unsigned short*)alloc((size_t)NTOK * DMODEL * 2);
    unsigned short* xz_bf = (unsigned short*)alloc((size_t)NTOK * 2 * DINNER * 2);
    unsigned short* xm_bf = (unsigned short*)alloc((size_t)NTOK * DINNER * 2);
    float* xp_part = (float*)alloc((size_t)XSPK * NTOK * XDS * 4);
    float* out_part = (float*)alloc((size_t)4 * NTOK * DMODEL * 4);
    float* BC     = (float*)alloc((size_t)NTOK * 32 * 4);
    unsigned short* dtA_bf = (unsigned short*)alloc((size_t)NTOK * DTRANK * 2);
    unsigned short* dt_bf = (unsigned short*)alloc((size_t)NTOK * DINNER * 2);
    unsigned short* y_bf = (unsigned short*)alloc((size_t)NTOK * DINNER * 2);
    float* h_end  = (float*)alloc((size_t)GCH * 2 * 16 * DINNER * 4);
    float* h_in   = (float*)alloc((size_t)GCH * 2 * 16 * DINNER * 4);
    float* S_chunk = (float*)alloc((size_t)GCH * 2 * DINNER * 4);
    int n_inw  = 4 * 2 * DINNER * DMODEL;
    int n_xpw  = 4 * 96 * DINNER;
    int n_dtw  = 4 * DINNER * DTRANK;
    int n_outw = 4 * DMODEL * DINNER;
    unsigned short* wbf_in  = (unsigned short*)alloc((size_t)n_inw * 2);
    unsigned short* wbf_xp  = (unsigned short*)alloc((size_t)n_xpw * 2);
    unsigned short* wbf_dt  = (unsigned short*)alloc((size_t)n_dtw * 2);
    unsigned short* wbf_out = (unsigned short*)alloc((size_t)n_outw * 2);

    // counts in 16-elem groups (all sizes divisible by 16)
    int c0 = n_inw / 16;
    int c1 = c0 + n_xpw / 16;
    int c2 = c1 + n_dtw / 16;
    int c3 = c2 + n_outw / 16;
    f32_to_bf16_4<<<(c3 + 255) / 256, 256, 0, stream>>>(
        in_w, wbf_in, c0, xp_w, wbf_xp, c1, dt_w, wbf_dt, c2, out_w, wbf_out, c3);

    // LN also copies x into x_res (replaces the memcpy)
    ln_kernel<<<NTOK, 256, 0, stream>>>(x_in, x_res, ln_g, ln_b, xn_bf);

    for (int L = 0; L < 4; ++L) {
        const unsigned short* w_in  = wbf_in  + (size_t)L * 2 * DINNER * DMODEL;
        const float*          w_cv  = conv_w  + (size_t)L * DINNER * 4;
        const float*          b_cv  = conv_b  + (size_t)L * DINNER;
        const unsigned short* w_xp  = wbf_xp  + (size_t)L * 96 * DINNER;
        const unsigned short* w_dt  = wbf_dt  + (size_t)L * DINNER * DTRANK;
        const float*          b_dt  = dt_b    + (size_t)L * DINNER;
        const float*          al    = A_logp  + (size_t)L * DINNER * DSTATE;
        const float*          dskl  = Dsk     + (size_t)L * DINNER;
        const unsigned short* w_out = wbf_out + (size_t)L * DMODEL * DINNER;

        // in_proj: [2048 x 4096 x 1024] -> bf16, 128x64 tile, 1024 blocks (4/CU)
        gemm64<<<dim3(64, 16, 1), 256, 0, stream>>>(
            xn_bf, w_in, xz_bf, nullptr, NTOK, 2 * DINNER, DMODEL, 2 * DINNER, 2);
        conv_silu<<<NTOK * (DINNER / 8) / 256, 256, 0, stream>>>(xz_bf, w_cv, b_cv, xm_bf);
        // x_proj: [2048 x 128(96) x 2048], split-K 8 -> f32 partials
        gemm64<<<dim3(2, 16, XSPK), 256, 0, stream>>>(
            xm_bf, w_xp, xp_part, nullptr, NTOK, XDS, DINNER, 96, 0);
        reduce_xp<<<NTOK * XDS / 256, 256, 0, stream>>>(xp_part, dtA_bf, BC);
        // dt_proj: [2048 x 2048 x 64], fused bias+softplus -> bf16 (MFMA, not VALU)
        gemm64<<<dim3(32, 16, 1), 256, 0, stream>>>(
            dtA_bf, w_dt, dt_bf, b_dt, NTOK, DINNER, DTRANK, DINNER, 3);
        scan_a<<<GCH * 16, 256, 0, stream>>>(dt_bf, xm_bf, BC, al, h_end, S_chunk);
        scan_b<<<2 * 16 * DINNER / 256, 256, 0, stream>>>(al, S_chunk, h_end, h_in);
        scan_c<<<GCH * 16, 256, 0, stream>>>(dt_bf, xm_bf, BC, al, dskl, xz_bf,
                                             h_in, y_bf);
        // out_proj: [2048 x 1024 x 2048], split-K 4 -> 1024 blocks (4/CU), KT=16
        gemm64<<<dim3(16, 16, 4), 256, 0, stream>>>(
            y_bf, w_out, out_part, nullptr, NTOK, DMODEL, DINNER, DMODEL, 0);
        // fused: x_res += p0+p1+p2+p3; LN -> next xn (bf16) or final out (f32)
        residual_ln<<<NTOK, 256, 0, stream>>>(
            x_res, out_part, out_part + (size_t)NTOK * DMODEL,
            out_part + (size_t)2 * NTOK * DMODEL, out_part + (size_t)3 * NTOK * DMODEL,
            ln_g, ln_b, (L < 3) ? xn_bf : nullptr, (L < 3) ? nullptr : outp);
    }
}

// Round 11
// 870.751 us; speedup vs baseline: 2.8895x; 1.0317x over previous
//
#include <hip/hip_runtime.h>

#define NTOK 2048      // BATCH*SEQ
#define SEQL 1024
#define DMODEL 1024
#define DINNER 2048
#define DSTATE 16
#define DTRANK 64
#define GCH 64         // scan chunks (R10: 128 regressed; 64 is the measured optimum)
#define LC 16          // steps per chunk
#define XDS 128        // padded xp-GEMM N (96 -> 128)
#define XSPK 8         // x_proj split-K factor (proven config)

typedef __attribute__((ext_vector_type(8))) short short8;
typedef __attribute__((ext_vector_type(4))) float float4v;

__device__ __forceinline__ unsigned short f2bf(float f) {
    unsigned u = __float_as_uint(f);
    unsigned r = u + 0x7FFFu + ((u >> 16) & 1u);
    return (unsigned short)(r >> 16);
}
__device__ __forceinline__ float bf2f(unsigned short h) {
    return __uint_as_float(((unsigned)h) << 16);
}

// ---------------- fused f32 -> bf16 weight conversion, 16 elems/thread ----------------
__global__ __launch_bounds__(256) void f32_to_bf16_4(
    const float* __restrict__ s0, unsigned short* __restrict__ d0, int c0,
    const float* __restrict__ s1, unsigned short* __restrict__ d1, int c1,
    const float* __restrict__ s2, unsigned short* __restrict__ d2, int c2,
    const float* __restrict__ s3, unsigned short* __restrict__ d3, int c3) {
    int i = blockIdx.x * 256 + threadIdx.x;      // i indexes 16-elem groups
    if (i >= c3) return;
    const float* s; unsigned short* dd; int j;
    if (i < c0)      { s = s0; dd = d0; j = i; }
    else if (i < c1) { s = s1; dd = d1; j = i - c0; }
    else if (i < c2) { s = s2; dd = d2; j = i - c1; }
    else             { s = s3; dd = d3; j = i - c2; }
    float4 a = ((const float4*)s)[4 * j];
    float4 b = ((const float4*)s)[4 * j + 1];
    float4 c = ((const float4*)s)[4 * j + 2];
    float4 d = ((const float4*)s)[4 * j + 3];
    uint4 v0, v1;
    v0.x = (unsigned)f2bf(a.x) | ((unsigned)f2bf(a.y) << 16);
    v0.y = (unsigned)f2bf(a.z) | ((unsigned)f2bf(a.w) << 16);
    v0.z = (unsigned)f2bf(b.x) | ((unsigned)f2bf(b.y) << 16);
    v0.w = (unsigned)f2bf(b.z) | ((unsigned)f2bf(b.w) << 16);
    v1.x = (unsigned)f2bf(c.x) | ((unsigned)f2bf(c.y) << 16);
    v1.y = (unsigned)f2bf(c.z) | ((unsigned)f2bf(c.w) << 16);
    v1.z = (unsigned)f2bf(d.x) | ((unsigned)f2bf(d.y) << 16);
    v1.w = (unsigned)f2bf(d.z) | ((unsigned)f2bf(d.w) << 16);
    ((uint4*)dd)[2 * j]     = v0;
    ((uint4*)dd)[2 * j + 1] = v1;
}

// ---------------- LayerNorm (prologue): f32 in -> bf16 out, also copies x into x_res ----------------
__global__ __launch_bounds__(256) void ln_kernel(
    const float* __restrict__ x, float* __restrict__ x_copy,
    const float* __restrict__ g, const float* __restrict__ b,
    unsigned short* __restrict__ out_bf) {
    int row = blockIdx.x;
    int t = threadIdx.x;
    float4 v = ((const float4*)(x + (size_t)row * DMODEL))[t];
    ((float4*)(x_copy + (size_t)row * DMODEL))[t] = v;
    float s  = v.x + v.y + v.z + v.w;
    float ss = v.x*v.x + v.y*v.y + v.z*v.z + v.w*v.w;
    for (int o = 32; o; o >>= 1) { s += __shfl_xor(s, o); ss += __shfl_xor(ss, o); }
    __shared__ float red[8];
    int wv = t >> 6;
    if ((t & 63) == 0) { red[wv * 2] = s; red[wv * 2 + 1] = ss; }
    __syncthreads();
    s  = red[0] + red[2] + red[4] + red[6];
    ss = red[1] + red[3] + red[5] + red[7];
    float mu = s * (1.f / DMODEL);
    float rstd = rsqrtf(ss * (1.f / DMODEL) - mu * mu + 1e-5f);
    float4 gv = ((const float4*)g)[t];
    float4 bv = ((const float4*)b)[t];
    ((ushort4*)out_bf)[row * 256 + t] = make_ushort4(
        f2bf((v.x - mu) * rstd * gv.x + bv.x),
        f2bf((v.y - mu) * rstd * gv.y + bv.y),
        f2bf((v.z - mu) * rstd * gv.z + bv.z),
        f2bf((v.w - mu) * rstd * gv.w + bv.w));
}

// ---------------- fused: x_res += p0+p1+p2+p3 ; LN(x_res) -> bf16 (or f32 final) ----------------
__global__ __launch_bounds__(256) void residual_ln(
    float* __restrict__ x_res, const float* __restrict__ p0,
    const float* __restrict__ p1, const float* __restrict__ p2,
    const float* __restrict__ p3, const float* __restrict__ g,
    const float* __restrict__ b, unsigned short* __restrict__ out_bf,
    float* __restrict__ out_f32) {
    int row = blockIdx.x;
    int t = threadIdx.x;
    size_t o4 = (size_t)row * 256 + t;
    float4 v  = ((const float4*)x_res)[o4];
    float4 a0 = ((const float4*)p0)[o4];
    float4 a1 = ((const float4*)p1)[o4];
    float4 a2 = ((const float4*)p2)[o4];
    float4 a3 = ((const float4*)p3)[o4];
    v.x += (a0.x + a1.x) + (a2.x + a3.x);
    v.y += (a0.y + a1.y) + (a2.y + a3.y);
    v.z += (a0.z + a1.z) + (a2.z + a3.z);
    v.w += (a0.w + a1.w) + (a2.w + a3.w);
    ((float4*)x_res)[o4] = v;
    float s  = v.x + v.y + v.z + v.w;
    float ss = v.x*v.x + v.y*v.y + v.z*v.z + v.w*v.w;
    for (int o = 32; o; o >>= 1) { s += __shfl_xor(s, o); ss += __shfl_xor(ss, o); }
    __shared__ float red[8];
    int wv = t >> 6;
    if ((t & 63) == 0) { red[wv * 2] = s; red[wv * 2 + 1] = ss; }
    __syncthreads();
    s  = red[0] + red[2] + red[4] + red[6];
    ss = red[1] + red[3] + red[5] + red[7];
    float mu = s * (1.f / DMODEL);
    float rstd = rsqrtf(ss * (1.f / DMODEL) - mu * mu + 1e-5f);
    float4 gv = ((const float4*)g)[t];
    float4 bv = ((const float4*)b)[t];
    float o0 = (v.x - mu) * rstd * gv.x + bv.x;
    float o1 = (v.y - mu) * rstd * gv.y + bv.y;
    float o2 = (v.z - mu) * rstd * gv.z + bv.z;
    float o3 = (v.w - mu) * rstd * gv.w + bv.w;
    if (out_f32) {
        ((float4*)out_f32)[o4] = make_float4(o0, o1, o2, o3);
    } else {
        ((ushort4*)out_bf)[o4] = make_ushort4(f2bf(o0), f2bf(o1), f2bf(o2), f2bf(o3));
    }
}

// ---------------- GEMM: C[M,N] = A[M,K](bf16) * B[N,K]^T(bf16) ----------------
// 128x64 tile, 4 waves, depth-3 LDS pipeline (36 KB -> 4 blocks/CU).
// Modes: 0 = f32 store into partial z (Cv + z*M*N); 2 = bf16 store.
// R6: atomic split-K accumulate = 4x regression. R8: grid-barrier fusion = 10x.
// R9: dt_proj on VALU inside scan = 2.3x regression. R11: dt_proj via MFMA
// inside scan instead (matrix pipe is idle there).
#define BKG 32
__global__ __launch_bounds__(256) void gemm64(
    const unsigned short* __restrict__ A, const unsigned short* __restrict__ B,
    void* __restrict__ Cv, int M, int N, int K, int Nb, int mode) {
    __shared__ __attribute__((aligned(16))) unsigned short As[3][128 * BKG];
    __shared__ __attribute__((aligned(16))) unsigned short Bs[3][64 * BKG];
    int m0 = blockIdx.y * 128, n0 = blockIdx.x * 64;
    int Klocal = K / gridDim.z;
    int kstart = blockIdx.z * Klocal;
    int t = threadIdx.x;
    int lane = t & 63, w = t >> 6;
    int tr = lane & 15, quad = lane >> 4;
    int r_l = lane >> 2;
    int q_l = (lane & 3) ^ ((lane >> 3) & 3);      // swizzled 16B-unit
    int col_l = q_l * 8;

    float4v acc[2][4];
    for (int mi = 0; mi < 2; ++mi)
        for (int ni = 0; ni < 4; ++ni)
            acc[mi][ni] = (float4v){0.f, 0.f, 0.f, 0.f};

    auto stage = [&](int kt, int buf) {
        int kbase = kstart + kt * BKG;
#pragma unroll
        for (int j = 0; j < 2; ++j) {
            int c = w * 2 + j;
            const unsigned short* ga = A + (size_t)(m0 + c * 16 + r_l) * K + kbase + col_l;
            __builtin_amdgcn_global_load_lds(
                (const __attribute__((address_space(1))) void*)ga,
                (__attribute__((address_space(3))) void*)(&As[buf][c * 512]),
                16, 0, 0);
        }
        int brow = n0 + w * 16 + r_l;
        if (brow >= Nb) brow = Nb - 1;
        const unsigned short* gb = B + (size_t)brow * K + kbase + col_l;
        __builtin_amdgcn_global_load_lds(
            (const __attribute__((address_space(1))) void*)gb,
            (__attribute__((address_space(3))) void*)(&Bs[buf][w * 512]),
            16, 0, 0);
    };

    int KT = Klocal / BKG;
    stage(0, 0);
    if (KT > 1) stage(1, 1);
    int u_off = (tr * 4 + (quad ^ ((tr >> 1) & 3))) * 8;
    for (int kt = 0; kt < KT; ++kt) {
        int cur = kt % 3;
        if (kt + 2 < KT) stage(kt + 2, (kt + 2) % 3);
        asm volatile("" ::: "memory");
        int nleft = KT - kt - 1;
        if (nleft >= 2)      __builtin_amdgcn_s_waitcnt(0x0F76);  // vmcnt(6)
        else if (nleft == 1) __builtin_amdgcn_s_waitcnt(0x0F73);  // vmcnt(3)
        else                 __builtin_amdgcn_s_waitcnt(0x0F70);  // vmcnt(0)
        __builtin_amdgcn_s_barrier();
        asm volatile("" ::: "memory");
        short8 af[2], bfr[4];
#pragma unroll
        for (int i = 0; i < 2; ++i)
            af[i] = *(const short8*)(&As[cur][(w * 2 + i) * 512 + u_off]);
#pragma unroll
        for (int i = 0; i < 4; ++i)
            bfr[i] = *(const short8*)(&Bs[cur][i * 512 + u_off]);
#pragma unroll
        for (int mi = 0; mi < 2; ++mi)
#pragma unroll
            for (int ni = 0; ni < 4; ++ni)
                acc[mi][ni] = __builtin_amdgcn_mfma_f32_16x16x32_bf16(
                    af[mi], bfr[ni], acc[mi][ni], 0, 0, 0);
        asm volatile("" ::: "memory");
        __builtin_amdgcn_s_barrier();
        asm volatile("" ::: "memory");
    }
    // C/D layout (m89-verified): col = lane&15, row = (lane>>4)*4 + reg
    size_t zoff = (size_t)blockIdx.z * M * N;
    for (int mi = 0; mi < 2; ++mi)
        for (int ni = 0; ni < 4; ++ni) {
            int col = n0 + ni * 16 + tr;
            int rowb = m0 + w * 32 + mi * 16 + quad * 4;
            for (int r = 0; r < 4; ++r) {
                size_t off = (size_t)(rowb + r) * N + col;
                float val = acc[mi][ni][r];
                if (mode == 0) {
                    ((float*)Cv)[zoff + off] = val;
                } else {
                    ((unsigned short*)Cv)[off] = f2bf(val);
                }
            }
        }
}

// ---------------- reduce 8 xp partials -> dtA(bf16) + compact BC(f32) ----------------
__global__ __launch_bounds__(256) void reduce_xp(
    const float* __restrict__ part, unsigned short* __restrict__ dtA,
    float* __restrict__ BC) {
    int i = blockIdx.x * 256 + threadIdx.x;      // NTOK*128
    int row = i >> 7, col = i & 127;
    float s = 0.f;
#pragma unroll
    for (int z = 0; z < XSPK; ++z)
        s += part[(size_t)z * NTOK * XDS + i];
    if (col < 64) dtA[row * 64 + col] = f2bf(s);
    else if (col < 96) BC[row * 32 + (col - 64)] = s;
}

// ---------------- causal depthwise conv(4) + bias + silu; bf16 -> bf16, 8 ch/thread ----------------
__global__ __launch_bounds__(256) void conv_silu(
    const unsigned short* __restrict__ xz, const float* __restrict__ cw,
    const float* __restrict__ cb, unsigned short* __restrict__ xm_bf) {
    int i = blockIdx.x * 256 + threadIdx.x;   // NTOK * DINNER/8
    int c8 = i & (DINNER / 8 - 1);
    int tk = i >> 8;
    int l = tk & (SEQL - 1);
    int c = c8 * 8;
    const unsigned short* base = xz + (size_t)tk * (2 * DINNER) + c;
    short8 r3 = {0,0,0,0,0,0,0,0}, r2 = {0,0,0,0,0,0,0,0}, r1 = {0,0,0,0,0,0,0,0};
    if (l >= 3) r3 = *(const short8*)(base - 3 * 2 * DINNER);
    if (l >= 2) r2 = *(const short8*)(base - 2 * 2 * DINNER);
    if (l >= 1) r1 = *(const short8*)(base - 1 * 2 * DINNER);
    short8 r0 = *(const short8*)(base);
    short8 out;
#pragma unroll
    for (int j = 0; j < 8; ++j) {
        float4 wv = ((const float4*)cw)[c + j];
        float acc = cb[c + j]
            + bf2f((unsigned short)r3[j]) * wv.x
            + bf2f((unsigned short)r2[j]) * wv.y
            + bf2f((unsigned short)r1[j]) * wv.z
            + bf2f((unsigned short)r0[j]) * wv.w;
        float sv = acc / (1.f + expf(-acc));
        out[j] = (short)f2bf(sv);
    }
    *(short8*)(xm_bf + (size_t)tk * DINNER + c) = out;
}

// ---------------- scan phase A: MFMA dt-tile + local recurrence -> h_end, S ----------------
// Per block: dt tile [16 tok x 256 ch] = 32 MFMAs over K=64 (2 accumulating
// 16x16x32 per 16-ch tile; same accumulation order as the old dt_proj GEMM).
// A-frag: A[row=lane&15][k=quad*8+j] from staged dtA; B-frag: w_dt row
// (c)[k=quad*8+j] direct from global (L2-hot). C/D: col=lane&15, row=quad*4+r.
__global__ __launch_bounds__(256) void scan_a(
    const unsigned short* __restrict__ dtA, const unsigned short* __restrict__ wdt,
    const float* __restrict__ dtb, const unsigned short* __restrict__ xm_bf,
    const float* __restrict__ BC, const float* __restrict__ A_log,
    float* __restrict__ h_end, float* __restrict__ S_chunk) {
    int bid = blockIdx.x;                 // GCH*2*8 = 1024
    int g = bid >> 4, b = (bid >> 3) & 1, cbk = bid & 7;
    int tid = threadIdx.x;
    int c0 = cbk * 256;
    int c = c0 + tid;
    int rowbase = b * SEQL + g * LC;
    __shared__ float Bsh[LC][16];
    __shared__ __attribute__((aligned(16))) unsigned short dtash[LC * 64];
    __shared__ unsigned short dt_lds[LC * 256];
    {
        int li = tid >> 4, s = tid & 15;
        Bsh[li][s] = BC[((size_t)(rowbase + li)) * 32 + s];
        ((uint2*)dtash)[tid] = ((const uint2*)(dtA + (size_t)rowbase * 64))[tid];
    }
    __syncthreads();
    {
        int lane = tid & 63, wn = tid >> 6;
        int l15 = lane & 15, quad = lane >> 4;
        short8 a0 = *(const short8*)(dtash + l15 * 64 + quad * 8);
        short8 a1 = *(const short8*)(dtash + l15 * 64 + 32 + quad * 8);
#pragma unroll
        for (int nt = 0; nt < 4; ++nt) {
            int ch = wn * 64 + nt * 16 + l15;
            const unsigned short* wrow = wdt + (size_t)(c0 + ch) * 64;
            short8 b0 = *(const short8*)(wrow + quad * 8);
            short8 b1 = *(const short8*)(wrow + 32 + quad * 8);
            float4v acc = (float4v){0.f, 0.f, 0.f, 0.f};
            acc = __builtin_amdgcn_mfma_f32_16x16x32_bf16(a0, b0, acc, 0, 0, 0);
            acc = __builtin_amdgcn_mfma_f32_16x16x32_bf16(a1, b1, acc, 0, 0, 0);
            float bias = dtb[c0 + ch];
#pragma unroll
            for (int r = 0; r < 4; ++r) {
                float v2 = acc[r] + bias;
                float sp = (v2 > 15.f) ? v2 : log1pf(expf(v2));
                dt_lds[(quad * 4 + r) * 256 + ch] = f2bf(sp);
            }
        }
    }
    __syncthreads();
    float a_l2[16], h[16];
#pragma unroll
    for (int s = 0; s < 16; ++s) {
        a_l2[s] = -expf(A_log[c * 16 + s]) * 1.44269504f;
        h[s] = 0.f;
    }
    float S = 0.f;
    for (int i = 0; i < LC; ++i) {
        float dtv = bf2f(dt_lds[i * 256 + tid]);
        S += dtv;
        float u = bf2f(xm_bf[(size_t)(rowbase + i) * DINNER + c]);
        float bu = dtv * u;
#pragma unroll
        for (int s = 0; s < 16; ++s) {
            float dA = exp2f(dtv * a_l2[s]);
            h[s] = dA * h[s] + Bsh[i][s] * bu;
        }
    }
    int gb = g * 2 + b;
#pragma unroll
    for (int s = 0; s < 16; ++s)
        h_end[((size_t)gb * 16 + s) * DINNER + c] = h[s];
    S_chunk[(size_t)gb * DINNER + c] = S;
}

// ---------------- scan phase B: combine chunks -> h_in per chunk ----------------
__global__ __launch_bounds__(256) void scan_b(
    const float* __restrict__ A_log, const float* __restrict__ S_chunk,
    const float* __restrict__ h_end, float* __restrict__ h_in) {
    int idx = blockIdx.x * 256 + threadIdx.x;   // 2*16*2048 = 65536
    int c = idx & (DINNER - 1);
    int s = (idx >> 11) & 15;
    int b = idx >> 15;
    float a_l2 = -expf(A_log[c * 16 + s]) * 1.44269504f;
    float h = 0.f;
    for (int g = 0; g < GCH; ++g) {
        int gb = g * 2 + b;
        h_in[((size_t)gb * 16 + s) * DINNER + c] = h;
        float P = exp2f(a_l2 * S_chunk[(size_t)gb * DINNER + c]);
        h = P * h + h_end[((size_t)gb * 16 + s) * DINNER + c];
    }
}

// ---------------- scan phase C: MFMA dt-tile + seeded recurrence -> y ----------------
__global__ __launch_bounds__(256) void scan_c(
    const unsigned short* __restrict__ dtA, const unsigned short* __restrict__ wdt,
    const float* __restrict__ dtb, const unsigned short* __restrict__ xm_bf,
    const float* __restrict__ BC, const float* __restrict__ A_log,
    const float* __restrict__ D_skip, const unsigned short* __restrict__ xz,
    const float* __restrict__ h_in, unsigned short* __restrict__ y_bf) {
    int bid = blockIdx.x;                 // 1024
    int g = bid >> 4, b = (bid >> 3) & 1, cbk = bid & 7;
    int tid = threadIdx.x;
    int c0 = cbk * 256;
    int c = c0 + tid;
    int rowbase = b * SEQL + g * LC;
    __shared__ float BCsh[LC][32];
    __shared__ __attribute__((aligned(16))) unsigned short dtash[LC * 64];
    __shared__ unsigned short dt_lds[LC * 256];
    for (int r = 0; r < 2; ++r) {
        int e = tid + r * 256;
        int li = e >> 5, s = e & 31;
        BCsh[li][s] = BC[((size_t)(rowbase + li)) * 32 + s];
    }
    ((uint2*)dtash)[tid] = ((const uint2*)(dtA + (size_t)rowbase * 64))[tid];
    __syncthreads();
    {
        int lane = tid & 63, wn = tid >> 6;
        int l15 = lane & 15, quad = lane >> 4;
        short8 a0 = *(const short8*)(dtash + l15 * 64 + quad * 8);
        short8 a1 = *(const short8*)(dtash + l15 * 64 + 32 + quad * 8);
#pragma unroll
        for (int nt = 0; nt < 4; ++nt) {
            int ch = wn * 64 + nt * 16 + l15;
            const unsigned short* wrow = wdt + (size_t)(c0 + ch) * 64;
            short8 b0 = *(const short8*)(wrow + quad * 8);
            short8 b1 = *(const short8*)(wrow + 32 + quad * 8);
            float4v acc = (float4v){0.f, 0.f, 0.f, 0.f};
            acc = __builtin_amdgcn_mfma_f32_16x16x32_bf16(a0, b0, acc, 0, 0, 0);
            acc = __builtin_amdgcn_mfma_f32_16x16x32_bf16(a1, b1, acc, 0, 0, 0);
            float bias = dtb[c0 + ch];
#pragma unroll
            for (int r = 0; r < 4; ++r) {
                float v2 = acc[r] + bias;
                float sp = (v2 > 15.f) ? v2 : log1pf(expf(v2));
                dt_lds[(quad * 4 + r) * 256 + ch] = f2bf(sp);
            }
        }
    }
    __syncthreads();
    int gb = g * 2 + b;
    float a_l2[16], h[16];
#pragma unroll
    for (int s = 0; s < 16; ++s) {
        a_l2[s] = -expf(A_log[c * 16 + s]) * 1.44269504f;
        h[s] = h_in[((size_t)gb * 16 + s) * DINNER + c];
    }
    float dsk = D_skip[c];
    for (int i = 0; i < LC; ++i) {
        size_t off = (size_t)(rowbase + i) * DINNER + c;
        float dtv = bf2f(dt_lds[i * 256 + tid]);
        float u = bf2f(xm_bf[off]);
        float bu = dtv * u;
        float y = 0.f;
#pragma unroll
        for (int s = 0; s < 16; ++s) {
            float dA = exp2f(dtv * a_l2[s]);
            h[s] = dA * h[s] + BCsh[i][s] * bu;
            y += h[s] * BCsh[i][16 + s];
        }
        y += u * dsk;
        float zv = bf2f(xz[(size_t)(rowbase + i) * (2 * DINNER) + DINNER + c]);
        y *= zv / (1.f + expf(-zv));
        y_bf[off] = f2bf(y);
    }
}

extern "C" void kernel_launch(void* const* d_in, const int* in_sizes, int n_in,
                              void* d_out, int out_size, void* d_ws, size_t ws_size,
                              hipStream_t stream) {
    const float* x_in   = (const float*)d_in[0];
    const float* in_w   = (const float*)d_in[1];
    const float* conv_w = (const float*)d_in[2];
    const float* conv_b = (const float*)d_in[3];
    const float* xp_w   = (const float*)d_in[4];
    const float* dt_w   = (const float*)d_in[5];
    const float* dt_b   = (const float*)d_in[6];
    const float* A_logp = (const float*)d_in[7];
    const float* Dsk    = (const float*)d_in[8];
    const float* out_w  = (const float*)d_in[9];
    const float* ln_g   = (const float*)d_in[10];
    const float* ln_b   = (const float*)d_in[11];
    float* outp = (float*)d_out;

    char* p = (char*)d_ws;
    auto alloc = [&](size_t bytes) {
        void* r = (void*)p;
        p += (bytes + 255) & ~(size_t)255;
        return r;
    };
    float* x_res  = (float*)alloc((size_t)NTOK * DMODEL * 4);
    unsigned short* xn_bf = (unsigned short*)alloc((size_t)NTOK * DMODEL * 2);
    unsigned short* xz_bf = (unsigned short*)alloc((size_t)NTOK * 2 * DINNER * 2);
    unsigned short* xm_bf = (unsigned short*)alloc((size_t)NTOK * DINNER * 2);
    float* xp_part = (float*)alloc((size_t)XSPK * NTOK * XDS * 4);
    float* out_part = (float*)alloc((size_t)4 * NTOK * DMODEL * 4);
    float* BC     = (float*)alloc((size_t)NTOK * 32 * 4);
    unsigned short* dtA_bf = (unsigned short*)alloc((size_t)NTOK * DTRANK * 2);
    unsigned short* y_bf = (unsigned short*)alloc((size_t)NTOK * DINNER * 2);
    float* h_end  = (float*)alloc((size_t)GCH * 2 * 16 * DINNER * 4);
    float* h_in   = (float*)alloc((size_t)GCH * 2 * 16 * DINNER * 4);
    float* S_chunk = (float*)alloc((size_t)GCH * 2 * DINNER * 4);
    int n_inw  = 4 * 2 * DINNER * DMODEL;
    int n_xpw  = 4 * 96 * DINNER;
    int n_dtw  = 4 * DINNER * DTRANK;
    int n_outw = 4 * DMODEL * DINNER;
    unsigned short* wbf_in  = (unsigned short*)alloc((size_t)n_inw * 2);
    unsigned short* wbf_xp  = (unsigned short*)alloc((size_t)n_xpw * 2);
    unsigned short* wbf_dt  = (unsigned short*)alloc((size_t)n_dtw * 2);
    unsigned short* wbf_out = (unsigned short*)alloc((size_t)n_outw * 2);

    // counts in 16-elem groups (all sizes divisible by 16)
    int c0 = n_inw / 16;
    int c1 = c0 + n_xpw / 16;
    int c2 = c1 + n_dtw / 16;
    int c3 = c2 + n_outw / 16;
    f32_to_bf16_4<<<(c3 + 255) / 256, 256, 0, stream>>>(
        in_w, wbf_in, c0, xp_w, wbf_xp, c1, dt_w, wbf_dt, c2, out_w, wbf_out, c3);

    // LN also copies x into x_res (replaces the memcpy)
    ln_kernel<<<NTOK, 256, 0, stream>>>(x_in, x_res, ln_g, ln_b, xn_bf);

    for (int L = 0; L < 4; ++L) {
        const unsigned short* w_in  = wbf_in  + (size_t)L * 2 * DINNER * DMODEL;
        const float*          w_cv  = conv_w  + (size_t)L * DINNER * 4;
        const float*          b_cv  = conv_b  + (size_t)L * DINNER;
        const unsigned short* w_xp  = wbf_xp  + (size_t)L * 96 * DINNER;
        const unsigned short* w_dt  = wbf_dt  + (size_t)L * DINNER * DTRANK;
        const float*          b_dt  = dt_b    + (size_t)L * DINNER;
        const float*          al    = A_logp  + (size_t)L * DINNER * DSTATE;
        const float*          dskl  = Dsk     + (size_t)L * DINNER;
        const unsigned short* w_out = wbf_out + (size_t)L * DMODEL * DINNER;

        // in_proj: [2048 x 4096 x 1024] -> bf16, 128x64 tile, 1024 blocks (4/CU)
        gemm64<<<dim3(64, 16, 1), 256, 0, stream>>>(
            xn_bf, w_in, xz_bf, NTOK, 2 * DINNER, DMODEL, 2 * DINNER, 2);
        conv_silu<<<NTOK * (DINNER / 8) / 256, 256, 0, stream>>>(xz_bf, w_cv, b_cv, xm_bf);
        // x_proj: [2048 x 128(96) x 2048], split-K 8 -> f32 partials
        gemm64<<<dim3(2, 16, XSPK), 256, 0, stream>>>(
            xm_bf, w_xp, xp_part, NTOK, XDS, DINNER, 96, 0);
        reduce_xp<<<NTOK * XDS / 256, 256, 0, stream>>>(xp_part, dtA_bf, BC);
        // scan (dt_proj computed in-kernel via MFMA; dt_proj dispatch removed)
        scan_a<<<GCH * 16, 256, 0, stream>>>(dtA_bf, w_dt, b_dt, xm_bf, BC, al,
                                             h_end, S_chunk);
        scan_b<<<2 * 16 * DINNER / 256, 256, 0, stream>>>(al, S_chunk, h_end, h_in);
        scan_c<<<GCH * 16, 256, 0, stream>>>(dtA_bf, w_dt, b_dt, xm_bf, BC, al,
                                             dskl, xz_bf, h_in, y_bf);
        // out_proj: [2048 x 1024 x 2048], split-K 4 -> 1024 blocks (4/CU), KT=16
        gemm64<<<dim3(16, 16, 4), 256, 0, stream>>>(
            y_bf, w_out, out_part, NTOK, DMODEL, DINNER, DMODEL, 0);
        // fused: x_res += p0+p1+p2+p3; LN -> next xn (bf16) or final out (f32)
        residual_ln<<<NTOK, 256, 0, stream>>>(
            x_res, out_part, out_part + (size_t)NTOK * DMODEL,
            out_part + (size_t)2 * NTOK * DMODEL, out_part + (size_t)3 * NTOK * DMODEL,
            ln_g, ln_b, (L < 3) ? xn_bf : nullptr, (L < 3) ? nullptr : outp);
    }
}

// Round 13
// 704.928 us; speedup vs baseline: 3.5692x; 1.2352x over previous
//
#include <hip/hip_runtime.h>

#define NTOK 2048      // BATCH*SEQ
#define SEQL 1024
#define DMODEL 1024
#define DINNER 2048
#define DSTATE 16
#define DTRANK 64
#define GCH 64         // scan chunks (R10: 128 regressed; 64 is the measured optimum)
#define LC 16          // steps per chunk
#define XDS 128        // padded xp-GEMM N (96 -> 128)
#define XSPK 8         // x_proj split-K factor (proven config)
#define DTP 264        // dt_lds padded row stride (kills 4-way write conflict)

typedef __attribute__((ext_vector_type(8))) short short8;
typedef __attribute__((ext_vector_type(4))) float float4v;

__device__ __forceinline__ unsigned short f2bf(float f) {
    unsigned u = __float_as_uint(f);
    unsigned r = u + 0x7FFFu + ((u >> 16) & 1u);
    return (unsigned short)(r >> 16);
}
__device__ __forceinline__ float bf2f(unsigned short h) {
    return __uint_as_float(((unsigned)h) << 16);
}

// Raw HW transcendentals via compiler builtins (single VOP1 each, hazard-safe:
// unlike inline asm, the compiler knows the trans-op wait-state rules).
// Without fast-math hipcc lowers exp2f/expf/log1pf to ocml wrappers (5-20 ops);
// R11 counters: scan VALUBusy 73-77% => VALU-throughput-bound, so this matters.
// All inputs range-safe; outputs bf16-bound, so 1-ULP HW precision is free.
#define LOG2E 1.44269504f
#define LN2   0.69314718f
__device__ __forceinline__ float fexp2(float x) { return __builtin_amdgcn_exp2f(x); }
__device__ __forceinline__ float flog2(float x) { return __builtin_amdgcn_logf(x); }
__device__ __forceinline__ float frcp(float x)  { return __builtin_amdgcn_rcpf(x); }
__device__ __forceinline__ float fsoftplus(float x) {
    return (x > 15.f) ? x : LN2 * flog2(1.f + fexp2(x * LOG2E));
}
__device__ __forceinline__ float fsilu(float x) {
    return x * frcp(1.f + fexp2(-LOG2E * x));
}

// ---------------- fused f32 -> bf16 weight conversion, 16 elems/thread ----------------
__global__ __launch_bounds__(256) void f32_to_bf16_4(
    const float* __restrict__ s0, unsigned short* __restrict__ d0, int c0,
    const float* __restrict__ s1, unsigned short* __restrict__ d1, int c1,
    const float* __restrict__ s2, unsigned short* __restrict__ d2, int c2,
    const float* __restrict__ s3, unsigned short* __restrict__ d3, int c3) {
    int i = blockIdx.x * 256 + threadIdx.x;      // i indexes 16-elem groups
    if (i >= c3) return;
    const float* s; unsigned short* dd; int j;
    if (i < c0)      { s = s0; dd = d0; j = i; }
    else if (i < c1) { s = s1; dd = d1; j = i - c0; }
    else if (i < c2) { s = s2; dd = d2; j = i - c1; }
    else             { s = s3; dd = d3; j = i - c2; }
    float4 a = ((const float4*)s)[4 * j];
    float4 b = ((const float4*)s)[4 * j + 1];
    float4 c = ((const float4*)s)[4 * j + 2];
    float4 d = ((const float4*)s)[4 * j + 3];
    uint4 v0, v1;
    v0.x = (unsigned)f2bf(a.x) | ((unsigned)f2bf(a.y) << 16);
    v0.y = (unsigned)f2bf(a.z) | ((unsigned)f2bf(a.w) << 16);
    v0.z = (unsigned)f2bf(b.x) | ((unsigned)f2bf(b.y) << 16);
    v0.w = (unsigned)f2bf(b.z) | ((unsigned)f2bf(b.w) << 16);
    v1.x = (unsigned)f2bf(c.x) | ((unsigned)f2bf(c.y) << 16);
    v1.y = (unsigned)f2bf(c.z) | ((unsigned)f2bf(c.w) << 16);
    v1.z = (unsigned)f2bf(d.x) | ((unsigned)f2bf(d.y) << 16);
    v1.w = (unsigned)f2bf(d.z) | ((unsigned)f2bf(d.w) << 16);
    ((uint4*)dd)[2 * j]     = v0;
    ((uint4*)dd)[2 * j + 1] = v1;
}

// ---------------- LayerNorm (prologue): f32 in -> bf16 out, also copies x into x_res ----------------
__global__ __launch_bounds__(256) void ln_kernel(
    const float* __restrict__ x, float* __restrict__ x_copy,
    const float* __restrict__ g, const float* __restrict__ b,
    unsigned short* __restrict__ out_bf) {
    int row = blockIdx.x;
    int t = threadIdx.x;
    float4 v = ((const float4*)(x + (size_t)row * DMODEL))[t];
    ((float4*)(x_copy + (size_t)row * DMODEL))[t] = v;
    float s  = v.x + v.y + v.z + v.w;
    float ss = v.x*v.x + v.y*v.y + v.z*v.z + v.w*v.w;
    for (int o = 32; o; o >>= 1) { s += __shfl_xor(s, o); ss += __shfl_xor(ss, o); }
    __shared__ float red[8];
    int wv = t >> 6;
    if ((t & 63) == 0) { red[wv * 2] = s; red[wv * 2 + 1] = ss; }
    __syncthreads();
    s  = red[0] + red[2] + red[4] + red[6];
    ss = red[1] + red[3] + red[5] + red[7];
    float mu = s * (1.f / DMODEL);
    float rstd = rsqrtf(ss * (1.f / DMODEL) - mu * mu + 1e-5f);
    float4 gv = ((const float4*)g)[t];
    float4 bv = ((const float4*)b)[t];
    ((ushort4*)out_bf)[row * 256 + t] = make_ushort4(
        f2bf((v.x - mu) * rstd * gv.x + bv.x),
        f2bf((v.y - mu) * rstd * gv.y + bv.y),
        f2bf((v.z - mu) * rstd * gv.z + bv.z),
        f2bf((v.w - mu) * rstd * gv.w + bv.w));
}

// ---------------- fused: x_res += p0+p1+p2+p3 ; LN(x_res) -> bf16 (or f32 final) ----------------
__global__ __launch_bounds__(256) void residual_ln(
    float* __restrict__ x_res, const float* __restrict__ p0,
    const float* __restrict__ p1, const float* __restrict__ p2,
    const float* __restrict__ p3, const float* __restrict__ g,
    const float* __restrict__ b, unsigned short* __restrict__ out_bf,
    float* __restrict__ out_f32) {
    int row = blockIdx.x;
    int t = threadIdx.x;
    size_t o4 = (size_t)row * 256 + t;
    float4 v  = ((const float4*)x_res)[o4];
    float4 a0 = ((const float4*)p0)[o4];
    float4 a1 = ((const float4*)p1)[o4];
    float4 a2 = ((const float4*)p2)[o4];
    float4 a3 = ((const float4*)p3)[o4];
    v.x += (a0.x + a1.x) + (a2.x + a3.x);
    v.y += (a0.y + a1.y) + (a2.y + a3.y);
    v.z += (a0.z + a1.z) + (a2.z + a3.z);
    v.w += (a0.w + a1.w) + (a2.w + a3.w);
    ((float4*)x_res)[o4] = v;
    float s  = v.x + v.y + v.z + v.w;
    float ss = v.x*v.x + v.y*v.y + v.z*v.z + v.w*v.w;
    for (int o = 32; o; o >>= 1) { s += __shfl_xor(s, o); ss += __shfl_xor(ss, o); }
    __shared__ float red[8];
    int wv = t >> 6;
    if ((t & 63) == 0) { red[wv * 2] = s; red[wv * 2 + 1] = ss; }
    __syncthreads();
    s  = red[0] + red[2] + red[4] + red[6];
    ss = red[1] + red[3] + red[5] + red[7];
    float mu = s * (1.f / DMODEL);
    float rstd = rsqrtf(ss * (1.f / DMODEL) - mu * mu + 1e-5f);
    float4 gv = ((const float4*)g)[t];
    float4 bv = ((const float4*)b)[t];
    float o0 = (v.x - mu) * rstd * gv.x + bv.x;
    float o1 = (v.y - mu) * rstd * gv.y + bv.y;
    float o2 = (v.z - mu) * rstd * gv.z + bv.z;
    float o3 = (v.w - mu) * rstd * gv.w + bv.w;
    if (out_f32) {
        ((float4*)out_f32)[o4] = make_float4(o0, o1, o2, o3);
    } else {
        ((ushort4*)out_bf)[o4] = make_ushort4(f2bf(o0), f2bf(o1), f2bf(o2), f2bf(o3));
    }
}

// ---------------- GEMM: C[M,N] = A[M,K](bf16) * B[N,K]^T(bf16) ----------------
// 128x64 tile, 4 waves, depth-3 LDS pipeline (36 KB -> 4 blocks/CU).
// Modes: 0 = f32 store into partial z (Cv + z*M*N); 2 = bf16 store.
// R6: atomic split-K accumulate = 4x regression. R8: grid-barrier fusion = 10x.
// R9: dt_proj on VALU inside scan = 2.3x regression; R11 MFMA version = win.
#define BKG 32
__global__ __launch_bounds__(256) void gemm64(
    const unsigned short* __restrict__ A, const unsigned short* __restrict__ B,
    void* __restrict__ Cv, int M, int N, int K, int Nb, int mode) {
    __shared__ __attribute__((aligned(16))) unsigned short As[3][128 * BKG];
    __shared__ __attribute__((aligned(16))) unsigned short Bs[3][64 * BKG];
    int m0 = blockIdx.y * 128, n0 = blockIdx.x * 64;
    int Klocal = K / gridDim.z;
    int kstart = blockIdx.z * Klocal;
    int t = threadIdx.x;
    int lane = t & 63, w = t >> 6;
    int tr = lane & 15, quad = lane >> 4;
    int r_l = lane >> 2;
    int q_l = (lane & 3) ^ ((lane >> 3) & 3);      // swizzled 16B-unit
    int col_l = q_l * 8;

    float4v acc[2][4];
    for (int mi = 0; mi < 2; ++mi)
        for (int ni = 0; ni < 4; ++ni)
            acc[mi][ni] = (float4v){0.f, 0.f, 0.f, 0.f};

    auto stage = [&](int kt, int buf) {
        int kbase = kstart + kt * BKG;
#pragma unroll
        for (int j = 0; j < 2; ++j) {
            int c = w * 2 + j;
            const unsigned short* ga = A + (size_t)(m0 + c * 16 + r_l) * K + kbase + col_l;
            __builtin_amdgcn_global_load_lds(
                (const __attribute__((address_space(1))) void*)ga,
                (__attribute__((address_space(3))) void*)(&As[buf][c * 512]),
                16, 0, 0);
        }
        int brow = n0 + w * 16 + r_l;
        if (brow >= Nb) brow = Nb - 1;
        const unsigned short* gb = B + (size_t)brow * K + kbase + col_l;
        __builtin_amdgcn_global_load_lds(
            (const __attribute__((address_space(1))) void*)gb,
            (__attribute__((address_space(3))) void*)(&Bs[buf][w * 512]),
            16, 0, 0);
    };

    int KT = Klocal / BKG;
    stage(0, 0);
    if (KT > 1) stage(1, 1);
    int u_off = (tr * 4 + (quad ^ ((tr >> 1) & 3))) * 8;
    for (int kt = 0; kt < KT; ++kt) {
        int cur = kt % 3;
        if (kt + 2 < KT) stage(kt + 2, (kt + 2) % 3);
        asm volatile("" ::: "memory");
        int nleft = KT - kt - 1;
        if (nleft >= 2)      __builtin_amdgcn_s_waitcnt(0x0F76);  // vmcnt(6)
        else if (nleft == 1) __builtin_amdgcn_s_waitcnt(0x0F73);  // vmcnt(3)
        else                 __builtin_amdgcn_s_waitcnt(0x0F70);  // vmcnt(0)
        __builtin_amdgcn_s_barrier();
        asm volatile("" ::: "memory");
        short8 af[2], bfr[4];
#pragma unroll
        for (int i = 0; i < 2; ++i)
            af[i] = *(const short8*)(&As[cur][(w * 2 + i) * 512 + u_off]);
#pragma unroll
        for (int i = 0; i < 4; ++i)
            bfr[i] = *(const short8*)(&Bs[cur][i * 512 + u_off]);
#pragma unroll
        for (int mi = 0; mi < 2; ++mi)
#pragma unroll
            for (int ni = 0; ni < 4; ++ni)
                acc[mi][ni] = __builtin_amdgcn_mfma_f32_16x16x32_bf16(
                    af[mi], bfr[ni], acc[mi][ni], 0, 0, 0);
        asm volatile("" ::: "memory");
        __builtin_amdgcn_s_barrier();
        asm volatile("" ::: "memory");
    }
    // C/D layout (m89-verified): col = lane&15, row = (lane>>4)*4 + reg
    size_t zoff = (size_t)blockIdx.z * M * N;
    for (int mi = 0; mi < 2; ++mi)
        for (int ni = 0; ni < 4; ++ni) {
            int col = n0 + ni * 16 + tr;
            int rowb = m0 + w * 32 + mi * 16 + quad * 4;
            for (int r = 0; r < 4; ++r) {
                size_t off = (size_t)(rowb + r) * N + col;
                float val = acc[mi][ni][r];
                if (mode == 0) {
                    ((float*)Cv)[zoff + off] = val;
                } else {
                    ((unsigned short*)Cv)[off] = f2bf(val);
                }
            }
        }
}

// ---------------- reduce 8 xp partials -> dtA(bf16) + compact BC(f32) ----------------
__global__ __launch_bounds__(256) void reduce_xp(
    const float* __restrict__ part, unsigned short* __restrict__ dtA,
    float* __restrict__ BC) {
    int i = blockIdx.x * 256 + threadIdx.x;      // NTOK*128
    int row = i >> 7, col = i & 127;
    float s = 0.f;
#pragma unroll
    for (int z = 0; z < XSPK; ++z)
        s += part[(size_t)z * NTOK * XDS + i];
    if (col < 64) dtA[row * 64 + col] = f2bf(s);
    else if (col < 96) BC[row * 32 + (col - 64)] = s;
}

// ---------------- causal depthwise conv(4) + bias + silu; bf16 -> bf16, 8 ch/thread ----------------
__global__ __launch_bounds__(256) void conv_silu(
    const unsigned short* __restrict__ xz, const float* __restrict__ cw,
    const float* __restrict__ cb, unsigned short* __restrict__ xm_bf) {
    int i = blockIdx.x * 256 + threadIdx.x;   // NTOK * DINNER/8
    int c8 = i & (DINNER / 8 - 1);
    int tk = i >> 8;
    int l = tk & (SEQL - 1);
    int c = c8 * 8;
    const unsigned short* base = xz + (size_t)tk * (2 * DINNER) + c;
    short8 r3 = {0,0,0,0,0,0,0,0}, r2 = {0,0,0,0,0,0,0,0}, r1 = {0,0,0,0,0,0,0,0};
    if (l >= 3) r3 = *(const short8*)(base - 3 * 2 * DINNER);
    if (l >= 2) r2 = *(const short8*)(base - 2 * 2 * DINNER);
    if (l >= 1) r1 = *(const short8*)(base - 1 * 2 * DINNER);
    short8 r0 = *(const short8*)(base);
    short8 out;
#pragma unroll
    for (int j = 0; j < 8; ++j) {
        float4 wv = ((const float4*)cw)[c + j];
        float acc = cb[c + j]
            + bf2f((unsigned short)r3[j]) * wv.x
            + bf2f((unsigned short)r2[j]) * wv.y
            + bf2f((unsigned short)r1[j]) * wv.z
            + bf2f((unsigned short)r0[j]) * wv.w;
        out[j] = (short)f2bf(fsilu(acc));
    }
    *(short8*)(xm_bf + (size_t)tk * DINNER + c) = out;
}

// ---------------- scan phase A: MFMA dt-tile + local recurrence -> h_end, S ----------------
// Per block: dt tile [16 tok x 256 ch] = 32 MFMAs over K=64 (2 accumulating
// 16x16x32 per 16-ch tile; same accumulation order as the old dt_proj GEMM).
__global__ __launch_bounds__(256) void scan_a(
    const unsigned short* __restrict__ dtA, const unsigned short* __restrict__ wdt,
    const float* __restrict__ dtb, const unsigned short* __restrict__ xm_bf,
    const float* __restrict__ BC, const float* __restrict__ A_log,
    float* __restrict__ h_end, float* __restrict__ S_chunk) {
    int bid = blockIdx.x;                 // GCH*2*8 = 1024
    int g = bid >> 4, b = (bid >> 3) & 1, cbk = bid & 7;
    int tid = threadIdx.x;
    int c0 = cbk * 256;
    int c = c0 + tid;
    int rowbase = b * SEQL + g * LC;
    __shared__ float Bsh[LC][16];
    __shared__ __attribute__((aligned(16))) unsigned short dtash[LC * 64];
    __shared__ unsigned short dt_lds[LC * DTP];
    {
        int li = tid >> 4, s = tid & 15;
        Bsh[li][s] = BC[((size_t)(rowbase + li)) * 32 + s];
        ((uint2*)dtash)[tid] = ((const uint2*)(dtA + (size_t)rowbase * 64))[tid];
    }
    __syncthreads();
    {
        int lane = tid & 63, wn = tid >> 6;
        int l15 = lane & 15, quad = lane >> 4;
        short8 a0 = *(const short8*)(dtash + l15 * 64 + quad * 8);
        short8 a1 = *(const short8*)(dtash + l15 * 64 + 32 + quad * 8);
#pragma unroll
        for (int nt = 0; nt < 4; ++nt) {
            int ch = wn * 64 + nt * 16 + l15;
            const unsigned short* wrow = wdt + (size_t)(c0 + ch) * 64;
            short8 b0 = *(const short8*)(wrow + quad * 8);
            short8 b1 = *(const short8*)(wrow + 32 + quad * 8);
            float4v acc = (float4v){0.f, 0.f, 0.f, 0.f};
            acc = __builtin_amdgcn_mfma_f32_16x16x32_bf16(a0, b0, acc, 0, 0, 0);
            acc = __builtin_amdgcn_mfma_f32_16x16x32_bf16(a1, b1, acc, 0, 0, 0);
            float bias = dtb[c0 + ch];
#pragma unroll
            for (int r = 0; r < 4; ++r)
                dt_lds[(quad * 4 + r) * DTP + ch] = f2bf(fsoftplus(acc[r] + bias));
        }
    }
    __syncthreads();
    float a_l2[16], h[16];
#pragma unroll
    for (int s = 0; s < 16; ++s) {
        a_l2[s] = -fexp2(A_log[c * 16 + s] * LOG2E) * LOG2E;
        h[s] = 0.f;
    }
    float S = 0.f;
    for (int i = 0; i < LC; ++i) {
        float dtv = bf2f(dt_lds[i * DTP + tid]);
        S += dtv;
        float u = bf2f(xm_bf[(size_t)(rowbase + i) * DINNER + c]);
        float bu = dtv * u;
#pragma unroll
        for (int s = 0; s < 16; ++s) {
            float dA = fexp2(dtv * a_l2[s]);
            h[s] = dA * h[s] + Bsh[i][s] * bu;
        }
    }
    int gb = g * 2 + b;
#pragma unroll
    for (int s = 0; s < 16; ++s)
        h_end[((size_t)gb * 16 + s) * DINNER + c] = h[s];
    S_chunk[(size_t)gb * DINNER + c] = S;
}

// ---------------- scan phase B: combine chunks -> h_in per chunk ----------------
__global__ __launch_bounds__(256) void scan_b(
    const float* __restrict__ A_log, const float* __restrict__ S_chunk,
    const float* __restrict__ h_end, float* __restrict__ h_in) {
    int idx = blockIdx.x * 256 + threadIdx.x;   // 2*16*2048 = 65536
    int c = idx & (DINNER - 1);
    int s = (idx >> 11) & 15;
    int b = idx >> 15;
    float a_l2 = -fexp2(A_log[c * 16 + s] * LOG2E) * LOG2E;
    float h = 0.f;
    for (int g = 0; g < GCH; ++g) {
        int gb = g * 2 + b;
        h_in[((size_t)gb * 16 + s) * DINNER + c] = h;
        float P = fexp2(a_l2 * S_chunk[(size_t)gb * DINNER + c]);
        h = P * h + h_end[((size_t)gb * 16 + s) * DINNER + c];
    }
}

// ---------------- scan phase C: MFMA dt-tile + seeded recurrence -> y ----------------
__global__ __launch_bounds__(256) void scan_c(
    const unsigned short* __restrict__ dtA, const unsigned short* __restrict__ wdt,
    const float* __restrict__ dtb, const unsigned short* __restrict__ xm_bf,
    const float* __restrict__ BC, const float* __restrict__ A_log,
    const float* __restrict__ D_skip, const unsigned short* __restrict__ xz,
    const float* __restrict__ h_in, unsigned short* __restrict__ y_bf) {
    int bid = blockIdx.x;                 // 1024
    int g = bid >> 4, b = (bid >> 3) & 1, cbk = bid & 7;
    int tid = threadIdx.x;
    int c0 = cbk * 256;
    int c = c0 + tid;
    int rowbase = b * SEQL + g * LC;
    __shared__ float BCsh[LC][32];
    __shared__ __attribute__((aligned(16))) unsigned short dtash[LC * 64];
    __shared__ unsigned short dt_lds[LC * DTP];
    for (int r = 0; r < 2; ++r) {
        int e = tid + r * 256;
        int li = e >> 5, s = e & 31;
        BCsh[li][s] = BC[((size_t)(rowbase + li)) * 32 + s];
    }
    ((uint2*)dtash)[tid] = ((const uint2*)(dtA + (size_t)rowbase * 64))[tid];
    __syncthreads();
    {
        int lane = tid & 63, wn = tid >> 6;
        int l15 = lane & 15, quad = lane >> 4;
        short8 a0 = *(const short8*)(dtash + l15 * 64 + quad * 8);
        short8 a1 = *(const short8*)(dtash + l15 * 64 + 32 + quad * 8);
#pragma unroll
        for (int nt = 0; nt < 4; ++nt) {
            int ch = wn * 64 + nt * 16 + l15;
            const unsigned short* wrow = wdt + (size_t)(c0 + ch) * 64;
            short8 b0 = *(const short8*)(wrow + quad * 8);
            short8 b1 = *(const short8*)(wrow + 32 + quad * 8);
            float4v acc = (float4v){0.f, 0.f, 0.f, 0.f};
            acc = __builtin_amdgcn_mfma_f32_16x16x32_bf16(a0, b0, acc, 0, 0, 0);
            acc = __builtin_amdgcn_mfma_f32_16x16x32_bf16(a1, b1, acc, 0, 0, 0);
            float bias = dtb[c0 + ch];
#pragma unroll
            for (int r = 0; r < 4; ++r)
                dt_lds[(quad * 4 + r) * DTP + ch] = f2bf(fsoftplus(acc[r] + bias));
        }
    }
    __syncthreads();
    int gb = g * 2 + b;
    float a_l2[16], h[16];
#pragma unroll
    for (int s = 0; s < 16; ++s) {
        a_l2[s] = -fexp2(A_log[c * 16 + s] * LOG2E) * LOG2E;
        h[s] = h_in[((size_t)gb * 16 + s) * DINNER + c];
    }
    float dsk = D_skip[c];
    for (int i = 0; i < LC; ++i) {
        size_t off = (size_t)(rowbase + i) * DINNER + c;
        float dtv = bf2f(dt_lds[i * DTP + tid]);
        float u = bf2f(xm_bf[off]);
        float bu = dtv * u;
        float y = 0.f;
#pragma unroll
        for (int s = 0; s < 16; ++s) {
            float dA = fexp2(dtv * a_l2[s]);
            h[s] = dA * h[s] + BCsh[i][s] * bu;
            y += h[s] * BCsh[i][16 + s];
        }
        y += u * dsk;
        float zv = bf2f(xz[(size_t)(rowbase + i) * (2 * DINNER) + DINNER + c]);
        y *= fsilu(zv);
        y_bf[off] = f2bf(y);
    }
}

extern "C" void kernel_launch(void* const* d_in, const int* in_sizes, int n_in,
                              void* d_out, int out_size, void* d_ws, size_t ws_size,
                              hipStream_t stream) {
    const float* x_in   = (const float*)d_in[0];
    const float* in_w   = (const float*)d_in[1];
    const float* conv_w = (const float*)d_in[2];
    const float* conv_b = (const float*)d_in[3];
    const float* xp_w   = (const float*)d_in[4];
    const float* dt_w   = (const float*)d_in[5];
    const float* dt_b   = (const float*)d_in[6];
    const float* A_logp = (const float*)d_in[7];
    const float* Dsk    = (const float*)d_in[8];
    const float* out_w  = (const float*)d_in[9];
    const float* ln_g   = (const float*)d_in[10];
    const float* ln_b   = (const float*)d_in[11];
    float* outp = (float*)d_out;

    char* p = (char*)d_ws;
    auto alloc = [&](size_t bytes) {
        void* r = (void*)p;
        p += (bytes + 255) & ~(size_t)255;
        return r;
    };
    float* x_res  = (float*)alloc((size_t)NTOK * DMODEL * 4);
    unsigned short* xn_bf = (unsigned short*)alloc((size_t)NTOK * DMODEL * 2);
    unsigned short* xz_bf = (unsigned short*)alloc((size_t)NTOK * 2 * DINNER * 2);
    unsigned short* xm_bf = (unsigned short*)alloc((size_t)NTOK * DINNER * 2);
    float* xp_part = (float*)alloc((size_t)XSPK * NTOK * XDS * 4);
    float* out_part = (float*)alloc((size_t)4 * NTOK * DMODEL * 4);
    float* BC     = (float*)alloc((size_t)NTOK * 32 * 4);
    unsigned short* dtA_bf = (unsigned short*)alloc((size_t)NTOK * DTRANK * 2);
    unsigned short* y_bf = (unsigned short*)alloc((size_t)NTOK * DINNER * 2);
    float* h_end  = (float*)alloc((size_t)GCH * 2 * 16 * DINNER * 4);
    float* h_in   = (float*)alloc((size_t)GCH * 2 * 16 * DINNER * 4);
    float* S_chunk = (float*)alloc((size_t)GCH * 2 * DINNER * 4);
    int n_inw  = 4 * 2 * DINNER * DMODEL;
    int n_xpw  = 4 * 96 * DINNER;
    int n_dtw  = 4 * DINNER * DTRANK;
    int n_outw = 4 * DMODEL * DINNER;
    unsigned short* wbf_in  = (unsigned short*)alloc((size_t)n_inw * 2);
    unsigned short* wbf_xp  = (unsigned short*)alloc((size_t)n_xpw * 2);
    unsigned short* wbf_dt  = (unsigned short*)alloc((size_t)n_dtw * 2);
    unsigned short* wbf_out = (unsigned short*)alloc((size_t)n_outw * 2);

    // counts in 16-elem groups (all sizes divisible by 16)
    int c0 = n_inw / 16;
    int c1 = c0 + n_xpw / 16;
    int c2 = c1 + n_dtw / 16;
    int c3 = c2 + n_outw / 16;
    f32_to_bf16_4<<<(c3 + 255) / 256, 256, 0, stream>>>(
        in_w, wbf_in, c0, xp_w, wbf_xp, c1, dt_w, wbf_dt, c2, out_w, wbf_out, c3);

    // LN also copies x into x_res (replaces the memcpy)
    ln_kernel<<<NTOK, 256, 0, stream>>>(x_in, x_res, ln_g, ln_b, xn_bf);

    for (int L = 0; L < 4; ++L) {
        const unsigned short* w_in  = wbf_in  + (size_t)L * 2 * DINNER * DMODEL;
        const float*          w_cv  = conv_w  + (size_t)L * DINNER * 4;
        const float*          b_cv  = conv_b  + (size_t)L * DINNER;
        const unsigned short* w_xp  = wbf_xp  + (size_t)L * 96 * DINNER;
        const unsigned short* w_dt  = wbf_dt  + (size_t)L * DINNER * DTRANK;
        const float*          b_dt  = dt_b    + (size_t)L * DINNER;
        const float*          al    = A_logp  + (size_t)L * DINNER * DSTATE;
        const float*          dskl  = Dsk     + (size_t)L * DINNER;
        const unsigned short* w_out = wbf_out + (size_t)L * DMODEL * DINNER;

        // in_proj: [2048 x 4096 x 1024] -> bf16, 128x64 tile, 1024 blocks (4/CU)
        gemm64<<<dim3(64, 16, 1), 256, 0, stream>>>(
            xn_bf, w_in, xz_bf, NTOK, 2 * DINNER, DMODEL, 2 * DINNER, 2);
        conv_silu<<<NTOK * (DINNER / 8) / 256, 256, 0, stream>>>(xz_bf, w_cv, b_cv, xm_bf);
        // x_proj: [2048 x 128(96) x 2048], split-K 8 -> f32 partials
        gemm64<<<dim3(2, 16, XSPK), 256, 0, stream>>>(
            xm_bf, w_xp, xp_part, NTOK, XDS, DINNER, 96, 0);
        reduce_xp<<<NTOK * XDS / 256, 256, 0, stream>>>(xp_part, dtA_bf, BC);
        // scan (dt_proj computed in-kernel via MFMA; raw HW transcendentals)
        scan_a<<<GCH * 16, 256, 0, stream>>>(dtA_bf, w_dt, b_dt, xm_bf, BC, al,
                                             h_end, S_chunk);
        scan_b<<<2 * 16 * DINNER / 256, 256, 0, stream>>>(al, S_chunk, h_end, h_in);
        scan_c<<<GCH * 16, 256, 0, stream>>>(dtA_bf, w_dt, b_dt, xm_bf, BC, al,
                                             dskl, xz_bf, h_in, y_bf);
        // out_proj: [2048 x 1024 x 2048], split-K 4 -> 1024 blocks (4/CU), KT=16
        gemm64<<<dim3(16, 16, 4), 256, 0, stream>>>(
            y_bf, w_out, out_part, NTOK, DMODEL, DINNER, DMODEL, 0);
        // fused: x_res += p0+p1+p2+p3; LN -> next xn (bf16) or final out (f32)
        residual_ln<<<NTOK, 256, 0, stream>>>(
            x_res, out_part, out_part + (size_t)NTOK * DMODEL,
            out_part + (size_t)2 * NTOK * DMODEL, out_part + (size_t)3 * NTOK * DMODEL,
            ln_g, ln_b, (L < 3) ? xn_bf : nullptr, (L < 3) ? nullptr : outp);
    }
}